// Round 5
// baseline (506.480 us; speedup 1.0000x reference)
//
#include <hip/hip_runtime.h>
#include <hip/hip_bf16.h>
#include <hip/hip_cooperative_groups.h>

namespace cg = cooperative_groups;

// N=25000, E=400000 (+N self loops), F_IN=64, HID=128, HEADS=4, OUT=256
// bf16 interior; agg = 2 waves/node, 4-edge unrolled readlane-broadcast gather.

#define LRELU(x) ((x) > 0.f ? (x) : 0.2f * (x))

typedef short bf16x8 __attribute__((ext_vector_type(8)));
typedef float f32x4 __attribute__((ext_vector_type(4)));

static __device__ __forceinline__ unsigned short f2b(float f) {
    union { float f; unsigned u; } x; x.f = f;
    unsigned r = x.u + 0x7fff + ((x.u >> 16) & 1);
    return (unsigned short)(r >> 16);
}
static __device__ __forceinline__ float blo(unsigned u) {
    union { unsigned u; float f; } x; x.u = u << 16; return x.f;
}
static __device__ __forceinline__ float bhi(unsigned u) {
    union { unsigned u; float f; } x; x.u = u & 0xffff0000u; return x.f;
}
static __device__ __forceinline__ float rl_f(float v, int c) {
    return __int_as_float(__builtin_amdgcn_readlane(__float_as_int(v), c));
}

// ---------------- CSR build: single cooperative kernel ------------------------
__global__ __launch_bounds__(256) void csr_build_coop(const int* __restrict__ ei, int E, int N,
                                                      int* __restrict__ deg, int* __restrict__ cursor,
                                                      float* __restrict__ pool, int* __restrict__ done,
                                                      int* __restrict__ rowptr, int* __restrict__ bsum,
                                                      int* __restrict__ boff,
                                                      int* __restrict__ esrc, int* __restrict__ edst) {
    cg::grid_group grid = cg::this_grid();
    int gtid = blockIdx.x * 256 + threadIdx.x;
    int nthr = gridDim.x * 256;
    __shared__ int sd[256];

    // phase 0: zero scratch
    for (int i = gtid; i < N; i += nthr) { deg[i] = 0; cursor[i] = 0; }
    if (gtid < 128) pool[gtid] = 0.f;
    if (gtid == 0) *done = 0;
    grid.sync();

    // phase 1: degree count
    for (int i = gtid; i < E + N; i += nthr) {
        int d = (i < E) ? ei[E + i] : (i - E);
        atomicAdd(&deg[d], 1);
    }
    grid.sync();

    // phase 2: per-256-chunk exclusive scan
    int nb = (N + 255) / 256;
    for (int b = blockIdx.x; b < nb; b += gridDim.x) {
        int i = b * 256 + threadIdx.x;
        int d = (i < N) ? deg[i] : 0;
        sd[threadIdx.x] = d;
        __syncthreads();
        for (int off = 1; off < 256; off <<= 1) {
            int v = (threadIdx.x >= off) ? sd[threadIdx.x - off] : 0;
            __syncthreads();
            sd[threadIdx.x] += v;
            __syncthreads();
        }
        if (i < N) rowptr[i] = sd[threadIdx.x] - d;
        if (threadIdx.x == 255) bsum[b] = sd[255];
        __syncthreads();
    }
    grid.sync();

    // phase 3: scan chunk sums (nb <= 256) on block 0
    if (blockIdx.x == 0) {
        int t = threadIdx.x;
        int d = (t < nb) ? bsum[t] : 0;
        sd[t] = d;
        __syncthreads();
        for (int off = 1; off < 256; off <<= 1) {
            int v = (t >= off) ? sd[t - off] : 0;
            __syncthreads();
            sd[t] += v;
            __syncthreads();
        }
        if (t < nb) boff[t] = sd[t] - d;
        if (t == 255) rowptr[N] = sd[255];
    }
    grid.sync();

    // phase 4: add chunk offsets
    for (int i = gtid; i < N; i += nthr) rowptr[i] += boff[i >> 8];
    grid.sync();

    // phase 5: scatter edges into CSR slots
    for (int i = gtid; i < E + N; i += nthr) {
        int s, d;
        if (i < E) { s = ei[i]; d = ei[E + i]; }
        else { s = i - E; d = s; }
        int pos = rowptr[d] + atomicAdd(&cursor[d], 1);
        esrc[pos] = s;
        edst[pos] = d;
    }
}

// ---------------- per-edge logits (CSR order) ---------------------------------
__global__ void edge_e1_kernel(const int* __restrict__ esrc, const int* __restrict__ edst,
                               const float4* __restrict__ as4, const float4* __restrict__ ad4,
                               float4* __restrict__ eb, int Etot) {
    int i = blockIdx.x * blockDim.x + threadIdx.x;
    if (i >= Etot) return;
    float4 u = as4[esrc[i]];
    float4 v = ad4[edst[i]];
    float4 e;
    e.x = LRELU(u.x + v.x); e.y = LRELU(u.y + v.y);
    e.z = LRELU(u.z + v.z); e.w = LRELU(u.w + v.w);
    eb[i] = e;
}

__global__ void edge_e2_kernel(const int* __restrict__ esrc, const int* __restrict__ edst,
                               const float* __restrict__ as, const float* __restrict__ ad,
                               float* __restrict__ eb, int Etot) {
    int i = blockIdx.x * blockDim.x + threadIdx.x;
    if (i >= Etot) return;
    float e = as[esrc[i]] + ad[edst[i]];
    eb[i] = LRELU(e);
}

// ---------------- prep: x->bf16 + 3 weight transposes (one dispatch) ----------
__global__ void prep_kernel(const float* __restrict__ x, const float* __restrict__ We,
                            const float* __restrict__ W1, const float* __restrict__ W2,
                            unsigned short* __restrict__ xb, unsigned short* __restrict__ WeT,
                            unsigned short* __restrict__ W1T, unsigned short* __restrict__ W2T,
                            int Nx) {
    int i = blockIdx.x * blockDim.x + threadIdx.x;
    if (i < Nx) { xb[i] = f2b(x[i]); return; }
    i -= Nx;
    if (i < 64 * 128) { int k = i >> 7, n = i & 127; WeT[n * 64 + k] = f2b(We[i]); return; }
    i -= 64 * 128;
    if (i < 128 * 512) { int k = i >> 9, n = i & 511; W1T[n * 128 + k] = f2b(W1[i]); return; }
    i -= 128 * 512;
    if (i < 512 * 128) { int k = i >> 7, n = i & 127; W2T[n * 512 + k] = f2b(W2[i]); return; }
}

// ---------------- MFMA bf16 NT GEMM: C[M,N] = A[M,K] @ Bt[N,K]^T --------------
template <int ACT>
__global__ __launch_bounds__(256) void gemm_mfma_nt(const unsigned short* __restrict__ A,
                                                    const unsigned short* __restrict__ Bt,
                                                    const float* __restrict__ bias,
                                                    unsigned short* __restrict__ C,
                                                    int M, int N, int K) {
    __shared__ __align__(16) unsigned short As[128 * 40];
    __shared__ __align__(16) unsigned short Bs[128 * 40];
    int tid = threadIdx.x;
    int gm0 = blockIdx.y * 128, gn0 = blockIdx.x * 128;
    int w = tid >> 6, lane = tid & 63;
    int wrow = (w >> 1) * 64, wcol = (w & 1) * 64;
    int l15 = lane & 15, quad = lane >> 4;

    f32x4 acc[4][4];
#pragma unroll
    for (int i = 0; i < 4; i++)
#pragma unroll
        for (int j = 0; j < 4; j++) acc[i][j] = {0.f, 0.f, 0.f, 0.f};

    for (int k0 = 0; k0 < K; k0 += 32) {
#pragma unroll
        for (int rr = 0; rr < 2; rr++) {
            int lin = tid + rr * 256;
            int row = lin >> 2;
            int cg = (lin & 3) * 8;
            int grow = gm0 + row; if (grow >= M) grow = M - 1;
            uint4 va = *(const uint4*)&A[(size_t)grow * K + k0 + cg];
            *(uint4*)&As[row * 40 + cg] = va;
            uint4 vb = *(const uint4*)&Bt[(size_t)(gn0 + row) * K + k0 + cg];
            *(uint4*)&Bs[row * 40 + cg] = vb;
        }
        __syncthreads();
        bf16x8 af[4], bfr[4];
#pragma unroll
        for (int i = 0; i < 4; i++) {
            af[i]  = *(const bf16x8*)&As[(wrow + i * 16 + l15) * 40 + quad * 8];
            bfr[i] = *(const bf16x8*)&Bs[(wcol + i * 16 + l15) * 40 + quad * 8];
        }
#pragma unroll
        for (int i = 0; i < 4; i++)
#pragma unroll
            for (int j = 0; j < 4; j++)
                acc[i][j] = __builtin_amdgcn_mfma_f32_16x16x32_bf16(af[i], bfr[j], acc[i][j], 0, 0, 0);
        __syncthreads();
    }

#pragma unroll
    for (int i = 0; i < 4; i++) {
        int row = gm0 + wrow + i * 16 + quad * 4;
#pragma unroll
        for (int j = 0; j < 4; j++) {
            int col = gn0 + wcol + j * 16 + l15;
            float bv = bias ? bias[col] : 0.f;
#pragma unroll
            for (int r = 0; r < 4; r++) {
                int gr = row + r;
                if (gr < M) {
                    float v = acc[i][j][r] + bv;
                    if (ACT == 1) v = fmaxf(v, 0.f);
                    C[(size_t)gr * N + col] = f2b(v);
                }
            }
        }
    }
}

// ---------------- alpha: one wave per node, bf16 row, shuffle reduce ----------
template <int H>
__global__ __launch_bounds__(256) void alpha_wave_kernel(const unsigned short* __restrict__ hb,
                                                         const float* __restrict__ a_src,
                                                         const float* __restrict__ a_dst,
                                                         float* __restrict__ as_out,
                                                         float* __restrict__ ad_out, int N) {
    int wid = (blockIdx.x * 256 + threadIdx.x) >> 6;
    int lane = threadIdx.x & 63;
    if (wid >= N) return;
    const int F = H * 128;
    float ds = 0.f, dd = 0.f;
    if (lane * 8 < F) {
        uint4 v = *(const uint4*)&hb[(size_t)wid * F + lane * 8];
        unsigned uu[4] = {v.x, v.y, v.z, v.w};
#pragma unroll
        for (int t = 0; t < 4; t++) {
            float f0 = blo(uu[t]), f1 = bhi(uu[t]);
            int c = lane * 8 + 2 * t;
            ds += f0 * a_src[c] + f1 * a_src[c + 1];
            dd += f0 * a_dst[c] + f1 * a_dst[c + 1];
        }
    }
#pragma unroll
    for (int o = 1; o < 16; o <<= 1) {
        ds += __shfl_xor(ds, o);
        dd += __shfl_xor(dd, o);
    }
    if ((lane & 15) == 0) {
        int h = lane >> 4;
        if (h < H) {
            as_out[wid * H + h] = ds;
            ad_out[wid * H + h] = dd;
        }
    }
}

// ---------------- GAT agg L1 (H=4): 2 waves/node, 4-edge unroll ---------------
__global__ __launch_bounds__(512) void gat_agg_l1(const unsigned short* __restrict__ hpre,
                                                  const float4* __restrict__ eb4,
                                                  const int* __restrict__ rowptr,
                                                  const int* __restrict__ esrc,
                                                  const float* __restrict__ bias,
                                                  unsigned short* __restrict__ out, int N) {
    __shared__ float wlds_all[8][256];
    __shared__ float part[4][64][9];
    int wv = threadIdx.x >> 6, lane = threadIdx.x & 63;
    int u = wv >> 1;
    int half = wv & 1;
    int n = blockIdx.x * 4 + u;
    bool active = n < N;
    int begin = 0, deg = 0;
    if (active) { begin = rowptr[n]; deg = rowptr[n + 1] - begin; }

    // pass 1: per-head max (both waves of the pair, contiguous reads)
    float4 m = {-3.4e38f, -3.4e38f, -3.4e38f, -3.4e38f};
    for (int base = 0; base < deg; base += 64) {
        int j = base + lane;
        if (j < deg) {
            float4 e = eb4[begin + j];
            m.x = fmaxf(m.x, e.x); m.y = fmaxf(m.y, e.y);
            m.z = fmaxf(m.z, e.z); m.w = fmaxf(m.w, e.w);
        }
    }
#pragma unroll
    for (int o = 32; o >= 1; o >>= 1) {
        m.x = fmaxf(m.x, __shfl_xor(m.x, o));
        m.y = fmaxf(m.y, __shfl_xor(m.y, o));
        m.z = fmaxf(m.z, __shfl_xor(m.z, o));
        m.w = fmaxf(m.w, __shfl_xor(m.w, o));
    }
    // pass 2: per-head sum of exp
    float4 s4 = {0.f, 0.f, 0.f, 0.f};
    for (int base = 0; base < deg; base += 64) {
        int j = base + lane;
        if (j < deg) {
            float4 e = eb4[begin + j];
            s4.x += __expf(e.x - m.x); s4.y += __expf(e.y - m.y);
            s4.z += __expf(e.z - m.z); s4.w += __expf(e.w - m.w);
        }
    }
#pragma unroll
    for (int o = 32; o >= 1; o >>= 1) {
        s4.x += __shfl_xor(s4.x, o); s4.y += __shfl_xor(s4.y, o);
        s4.z += __shfl_xor(s4.z, o); s4.w += __shfl_xor(s4.w, o);
    }
    float4 inv = {1.f / (s4.x + 1e-16f), 1.f / (s4.y + 1e-16f),
                  1.f / (s4.z + 1e-16f), 1.f / (s4.w + 1e-16f)};

    // pass 3: this wave gathers its half of the edges (4-edge unroll)
    int dhalf = (deg + 1) >> 1;
    int e0 = begin + half * dhalf;
    int e1 = begin + min(deg, dhalf * (half + 1));
    float* wlds = wlds_all[wv];
    float acc[8] = {};
    int h = lane >> 4;
    for (int base = e0; base < e1; base += 64) {
        int j = base + lane;
        int len = min(64, e1 - base);
        int s_l = 0;
        if (j < e1) {
            s_l = esrc[j];
            float4 e = eb4[j];
            float4 wv4;
            wv4.x = __expf(e.x - m.x) * inv.x;
            wv4.y = __expf(e.y - m.y) * inv.y;
            wv4.z = __expf(e.z - m.z) * inv.z;
            wv4.w = __expf(e.w - m.w) * inv.w;
            *(float4*)&wlds[lane * 4] = wv4;   // wave-private: no barrier needed
        }
        int c = 0;
        for (; c + 4 <= len; c += 4) {
            int s0 = __builtin_amdgcn_readlane(s_l, c);
            int s1 = __builtin_amdgcn_readlane(s_l, c + 1);
            int s2 = __builtin_amdgcn_readlane(s_l, c + 2);
            int s3 = __builtin_amdgcn_readlane(s_l, c + 3);
            uint4 h0 = *((const uint4*)(hpre + ((size_t)s0 << 9)) + lane);
            uint4 h1 = *((const uint4*)(hpre + ((size_t)s1 << 9)) + lane);
            uint4 h2 = *((const uint4*)(hpre + ((size_t)s2 << 9)) + lane);
            uint4 h3 = *((const uint4*)(hpre + ((size_t)s3 << 9)) + lane);
            float w0 = wlds[c * 4 + h];
            float w1 = wlds[c * 4 + 4 + h];
            float w2 = wlds[c * 4 + 8 + h];
            float w3 = wlds[c * 4 + 12 + h];
            acc[0] += w0 * blo(h0.x); acc[1] += w0 * bhi(h0.x);
            acc[2] += w0 * blo(h0.y); acc[3] += w0 * bhi(h0.y);
            acc[4] += w0 * blo(h0.z); acc[5] += w0 * bhi(h0.z);
            acc[6] += w0 * blo(h0.w); acc[7] += w0 * bhi(h0.w);
            acc[0] += w1 * blo(h1.x); acc[1] += w1 * bhi(h1.x);
            acc[2] += w1 * blo(h1.y); acc[3] += w1 * bhi(h1.y);
            acc[4] += w1 * blo(h1.z); acc[5] += w1 * bhi(h1.z);
            acc[6] += w1 * blo(h1.w); acc[7] += w1 * bhi(h1.w);
            acc[0] += w2 * blo(h2.x); acc[1] += w2 * bhi(h2.x);
            acc[2] += w2 * blo(h2.y); acc[3] += w2 * bhi(h2.y);
            acc[4] += w2 * blo(h2.z); acc[5] += w2 * bhi(h2.z);
            acc[6] += w2 * blo(h2.w); acc[7] += w2 * bhi(h2.w);
            acc[0] += w3 * blo(h3.x); acc[1] += w3 * bhi(h3.x);
            acc[2] += w3 * blo(h3.y); acc[3] += w3 * bhi(h3.y);
            acc[4] += w3 * blo(h3.z); acc[5] += w3 * bhi(h3.z);
            acc[6] += w3 * blo(h3.w); acc[7] += w3 * bhi(h3.w);
        }
        for (; c < len; c++) {
            int s0 = __builtin_amdgcn_readlane(s_l, c);
            uint4 h0 = *((const uint4*)(hpre + ((size_t)s0 << 9)) + lane);
            float w0 = wlds[c * 4 + h];
            acc[0] += w0 * blo(h0.x); acc[1] += w0 * bhi(h0.x);
            acc[2] += w0 * blo(h0.y); acc[3] += w0 * bhi(h0.y);
            acc[4] += w0 * blo(h0.z); acc[5] += w0 * bhi(h0.z);
            acc[6] += w0 * blo(h0.w); acc[7] += w0 * bhi(h0.w);
        }
    }
    // combine halves via LDS
    if (half == 1) {
#pragma unroll
        for (int t = 0; t < 8; t++) part[u][lane][t] = acc[t];
    }
    __syncthreads();
    if (active && half == 0) {
#pragma unroll
        for (int t = 0; t < 8; t++) acc[t] += part[u][lane][t];
        int f0 = lane * 8;
        unsigned pk[4];
#pragma unroll
        for (int k = 0; k < 4; k++) {
            float v0 = acc[2 * k] + bias[f0 + 2 * k];
            float v1 = acc[2 * k + 1] + bias[f0 + 2 * k + 1];
            v0 = v0 > 0.f ? v0 : (__expf(v0) - 1.f);
            v1 = v1 > 0.f ? v1 : (__expf(v1) - 1.f);
            pk[k] = (unsigned)f2b(v0) | ((unsigned)f2b(v1) << 16);
        }
        uint4 pv = {pk[0], pk[1], pk[2], pk[3]};
        *((uint4*)(out + (size_t)n * 512) + lane) = pv;
    }
}

// ---------------- GAT agg L2 (H=1): 2 waves/node, 4-edge unroll ---------------
__global__ __launch_bounds__(512) void gat_agg_l2(const unsigned short* __restrict__ hpre,
                                                  const float* __restrict__ eb,
                                                  const int* __restrict__ rowptr,
                                                  const int* __restrict__ esrc,
                                                  const float* __restrict__ bias,
                                                  float* __restrict__ out, int N) {
    __shared__ float part[4][64][2];
    int wv = threadIdx.x >> 6, lane = threadIdx.x & 63;
    int u = wv >> 1, half = wv & 1;
    int n = blockIdx.x * 4 + u;
    bool active = n < N;
    int begin = 0, deg = 0;
    if (active) { begin = rowptr[n]; deg = rowptr[n + 1] - begin; }

    float m = -3.4e38f;
    for (int base = 0; base < deg; base += 64) {
        int j = base + lane;
        if (j < deg) m = fmaxf(m, eb[begin + j]);
    }
#pragma unroll
    for (int o = 32; o >= 1; o >>= 1) m = fmaxf(m, __shfl_xor(m, o));

    float s = 0.f;
    for (int base = 0; base < deg; base += 64) {
        int j = base + lane;
        if (j < deg) s += __expf(eb[begin + j] - m);
    }
#pragma unroll
    for (int o = 32; o >= 1; o >>= 1) s += __shfl_xor(s, o);
    float inv = 1.f / (s + 1e-16f);

    int dhalf = (deg + 1) >> 1;
    int e0 = begin + half * dhalf;
    int e1 = begin + min(deg, dhalf * (half + 1));
    float acc0 = 0.f, acc1 = 0.f;
    for (int base = e0; base < e1; base += 64) {
        int j = base + lane;
        int len = min(64, e1 - base);
        int s_l = 0; float w_l = 0.f;
        if (j < e1) {
            s_l = esrc[j];
            w_l = __expf(eb[j] - m) * inv;
        }
        int c = 0;
        for (; c + 4 <= len; c += 4) {
            int sp0 = __builtin_amdgcn_readlane(s_l, c);
            int sp1 = __builtin_amdgcn_readlane(s_l, c + 1);
            int sp2 = __builtin_amdgcn_readlane(s_l, c + 2);
            int sp3 = __builtin_amdgcn_readlane(s_l, c + 3);
            unsigned u0 = *((const unsigned*)(hpre + ((size_t)sp0 << 7)) + lane);
            unsigned u1 = *((const unsigned*)(hpre + ((size_t)sp1 << 7)) + lane);
            unsigned u2 = *((const unsigned*)(hpre + ((size_t)sp2 << 7)) + lane);
            unsigned u3 = *((const unsigned*)(hpre + ((size_t)sp3 << 7)) + lane);
            float w0 = rl_f(w_l, c), w1 = rl_f(w_l, c + 1);
            float w2 = rl_f(w_l, c + 2), w3 = rl_f(w_l, c + 3);
            acc0 += w0 * blo(u0); acc1 += w0 * bhi(u0);
            acc0 += w1 * blo(u1); acc1 += w1 * bhi(u1);
            acc0 += w2 * blo(u2); acc1 += w2 * bhi(u2);
            acc0 += w3 * blo(u3); acc1 += w3 * bhi(u3);
        }
        for (; c < len; c++) {
            int sp0 = __builtin_amdgcn_readlane(s_l, c);
            float w0 = rl_f(w_l, c);
            unsigned u0 = *((const unsigned*)(hpre + ((size_t)sp0 << 7)) + lane);
            acc0 += w0 * blo(u0); acc1 += w0 * bhi(u0);
        }
    }
    if (half == 1) { part[u][lane][0] = acc0; part[u][lane][1] = acc1; }
    __syncthreads();
    if (active && half == 0) {
        acc0 += part[u][lane][0];
        acc1 += part[u][lane][1];
        float v0 = acc0 + bias[lane * 2];
        float v1 = acc1 + bias[lane * 2 + 1];
        v0 = v0 > 0.f ? v0 : (__expf(v0) - 1.f);
        v1 = v1 > 0.f ? v1 : (__expf(v1) - 1.f);
        float2 pv = {v0, v1};
        *(float2*)&out[(size_t)n * 128 + lane * 2] = pv;
    }
}

// ---------------- mean pool + final GEMV (fused via done-counter) -------------
__global__ __launch_bounds__(256) void pool_final_kernel(const float* __restrict__ o2,
                                                         float* __restrict__ pool,
                                                         int* __restrict__ done,
                                                         const float* __restrict__ Wout,
                                                         const float* __restrict__ bout,
                                                         float* __restrict__ out,
                                                         int N, int nblocks, float invN) {
    __shared__ float4 sred[256];
    int f4 = threadIdx.x & 31;
    int r = blockIdx.x * 256 + (threadIdx.x >> 5);
    float4 acc = {0.f, 0.f, 0.f, 0.f};
    for (int i = 0; i < 32; i++, r += 8) {
        if (r < N) {
            float4 v = *(const float4*)&o2[(size_t)r * 128 + f4 * 4];
            acc.x += v.x; acc.y += v.y; acc.z += v.z; acc.w += v.w;
        }
    }
    sred[threadIdx.x] = acc;
    __syncthreads();
    if (threadIdx.x < 32) {
        float4 t = sred[threadIdx.x];
#pragma unroll
        for (int k = 1; k < 8; k++) {
            float4 u = sred[threadIdx.x + 32 * k];
            t.x += u.x; t.y += u.y; t.z += u.z; t.w += u.w;
        }
        atomicAdd(&pool[f4 * 4 + 0], t.x);
        atomicAdd(&pool[f4 * 4 + 1], t.y);
        atomicAdd(&pool[f4 * 4 + 2], t.z);
        atomicAdd(&pool[f4 * 4 + 3], t.w);
    }
    __threadfence();
    __shared__ int isLast;
    if (threadIdx.x == 0) isLast = (atomicAdd(done, 1) == nblocks - 1);
    __syncthreads();
    if (isLast) {
        __shared__ float spool[128];
        if (threadIdx.x < 128) spool[threadIdx.x] = atomicAdd(&pool[threadIdx.x], 0.f);
        __syncthreads();
        int o = threadIdx.x;
        float a = 0.f;
        for (int k = 0; k < 128; k++) a += spool[k] * Wout[k * 256 + o];
        out[o] = a * invN + bout[o];
    }
}

// ---------------- launch ------------------------------------------------------
extern "C" void kernel_launch(void* const* d_in, const int* in_sizes, int n_in,
                              void* d_out, int out_size, void* d_ws, size_t ws_size,
                              hipStream_t stream) {
    const float* x      = (const float*)d_in[0];
    const int*   ei     = (const int*)d_in[1];
    const float* W_emb  = (const float*)d_in[2];
    const float* b_emb  = (const float*)d_in[3];
    const float* W1     = (const float*)d_in[4];
    const float* a1_src = (const float*)d_in[5];
    const float* a1_dst = (const float*)d_in[6];
    const float* b1     = (const float*)d_in[7];
    const float* W2     = (const float*)d_in[8];
    const float* a2_src = (const float*)d_in[9];
    const float* a2_dst = (const float*)d_in[10];
    const float* b2     = (const float*)d_in[11];
    const float* W_out  = (const float*)d_in[12];
    const float* b_out  = (const float*)d_in[13];
    float* out = (float*)d_out;

    const int N = in_sizes[0] / 64;   // 25000
    const int E = in_sizes[1] / 2;    // 400000
    const int Etot = E + N;

    char* ws = (char*)d_ws;
    size_t off = 0;
    auto alloc = [&](size_t bytes) -> void* {
        void* p = ws + off;
        off = (off + bytes + 255) & ~(size_t)255;
        return p;
    };
    typedef unsigned short u16;
    u16* xb    = (u16*)alloc((size_t)N * 64 * 2);
    u16* WeT   = (u16*)alloc((size_t)128 * 64 * 2);
    u16* W1T   = (u16*)alloc((size_t)512 * 128 * 2);
    u16* W2T   = (u16*)alloc((size_t)128 * 512 * 2);
    u16* h0b   = (u16*)alloc((size_t)N * 128 * 2);
    u16* h1b   = (u16*)alloc((size_t)N * 512 * 2);
    u16* o1b   = (u16*)alloc((size_t)N * 512 * 2);
    u16* h2b   = (u16*)alloc((size_t)N * 128 * 2);
    float* o2  = (float*)alloc((size_t)N * 128 * 4);
    float* as1 = (float*)alloc((size_t)N * 4 * 4);
    float* ad1 = (float*)alloc((size_t)N * 4 * 4);
    float* as2 = (float*)alloc((size_t)N * 4);
    float* ad2 = (float*)alloc((size_t)N * 4);
    float* pool = (float*)alloc(128 * 4);
    int* done   = (int*)alloc(256);
    int* rowptr = (int*)alloc((size_t)(N + 1) * 4);
    int* deg    = (int*)alloc((size_t)N * 4);
    int* cursor = (int*)alloc((size_t)N * 4);
    int* bsum   = (int*)alloc(256 * 4);
    int* boff   = (int*)alloc(256 * 4);
    int* esrc   = (int*)alloc((size_t)Etot * 4);
    int* edst   = (int*)alloc((size_t)Etot * 4);
    float* eb1  = (float*)alloc((size_t)Etot * 4 * 4);
    float* eb2  = (float*)alloc((size_t)Etot * 4);

    // CSR build: one cooperative dispatch (zero + count + scan + scatter)
    {
        const int* ei_ = ei; int E_ = E, N_ = N;
        int* deg_ = deg; int* cursor_ = cursor; float* pool_ = pool; int* done_ = done;
        int* rowptr_ = rowptr; int* bsum_ = bsum; int* boff_ = boff;
        int* esrc_ = esrc; int* edst_ = edst;
        void* args[] = {(void*)&ei_, (void*)&E_, (void*)&N_, (void*)&deg_, (void*)&cursor_,
                        (void*)&pool_, (void*)&done_, (void*)&rowptr_, (void*)&bsum_,
                        (void*)&boff_, (void*)&esrc_, (void*)&edst_};
        hipLaunchCooperativeKernel((void*)csr_build_coop, dim3(256), dim3(256), args, 0, stream);
    }

    // bf16 conversions + weight transposes (single dispatch)
    int Nx = N * 64;
    int prep_elems = Nx + 64 * 128 + 128 * 512 + 512 * 128;
    prep_kernel<<<(prep_elems + 255) / 256, 256, 0, stream>>>(x, W_emb, W1, W2, xb, WeT, W1T, W2T, Nx);

    int mtiles = (N + 127) / 128;
    gemm_mfma_nt<1><<<dim3(1, mtiles), 256, 0, stream>>>(xb, WeT, b_emb, h0b, N, 128, 64);
    gemm_mfma_nt<0><<<dim3(4, mtiles), 256, 0, stream>>>(h0b, W1T, nullptr, h1b, N, 512, 128);

    // layer-1 attention + aggregation
    int blocksE = (Etot + 255) / 256;
    alpha_wave_kernel<4><<<(N * 64 + 255) / 256, 256, 0, stream>>>(h1b, a1_src, a1_dst, as1, ad1, N);
    edge_e1_kernel<<<blocksE, 256, 0, stream>>>(esrc, edst, (const float4*)as1, (const float4*)ad1,
                                                (float4*)eb1, Etot);
    gat_agg_l1<<<(N + 3) / 4, 512, 0, stream>>>(h1b, (const float4*)eb1, rowptr, esrc, b1, o1b, N);

    gemm_mfma_nt<0><<<dim3(1, mtiles), 256, 0, stream>>>(o1b, W2T, nullptr, h2b, N, 128, 512);

    // layer-2 attention + aggregation
    alpha_wave_kernel<1><<<(N * 64 + 255) / 256, 256, 0, stream>>>(h2b, a2_src, a2_dst, as2, ad2, N);
    edge_e2_kernel<<<blocksE, 256, 0, stream>>>(esrc, edst, as2, ad2, eb2, Etot);
    gat_agg_l2<<<(N + 3) / 4, 512, 0, stream>>>(h2b, eb2, rowptr, esrc, b2, o2, N);

    // mean pool + final GEMV (one dispatch)
    int npb = (N + 255) / 256;
    pool_final_kernel<<<npb, 256, 0, stream>>>(o2, pool, done, W_out, b_out, out,
                                               N, npb, 1.f / (float)N);
}

// Round 6
// 329.949 us; speedup vs baseline: 1.5350x; 1.5350x over previous
//
#include <hip/hip_runtime.h>
#include <hip/hip_bf16.h>

// N=25000, E=400000 (+N self loops), F_IN=64, HID=128, HEADS=4, OUT=256
// bf16 interior; agg = 1 wave/node, 4-edge unrolled readlane-broadcast gather.
// NOTE: cooperative grid.sync measured ~30us/barrier on gfx950 — never use it
// to fuse cheap kernels (round-5 regression: 6-barrier CSR build = 180us).

#define LRELU(x) ((x) > 0.f ? (x) : 0.2f * (x))

typedef short bf16x8 __attribute__((ext_vector_type(8)));
typedef float f32x4 __attribute__((ext_vector_type(4)));

static __device__ __forceinline__ unsigned short f2b(float f) {
    union { float f; unsigned u; } x; x.f = f;
    unsigned r = x.u + 0x7fff + ((x.u >> 16) & 1);
    return (unsigned short)(r >> 16);
}
static __device__ __forceinline__ float blo(unsigned u) {
    union { unsigned u; float f; } x; x.u = u << 16; return x.f;
}
static __device__ __forceinline__ float bhi(unsigned u) {
    union { unsigned u; float f; } x; x.u = u & 0xffff0000u; return x.f;
}
static __device__ __forceinline__ float rl_f(float v, int c) {
    return __int_as_float(__builtin_amdgcn_readlane(__float_as_int(v), c));
}

// ---------------- zero scratch ------------------------------------------------
__global__ void zero_kernel(int* __restrict__ deg, int* __restrict__ cursor,
                            float* __restrict__ pool, int* __restrict__ done, int N) {
    int i = blockIdx.x * blockDim.x + threadIdx.x;
    if (i < N) deg[i] = 0;
    else if (i < 2 * N) cursor[i - N] = 0;
    else if (i < 2 * N + 128) pool[i - 2 * N] = 0.f;
    else if (i == 2 * N + 128) *done = 0;
}

// ---------------- CSR build (6 small kernels — proven fast) -------------------
__global__ void deg_count_kernel(const int* __restrict__ ei, int E, int N, int* __restrict__ deg) {
    int i = blockIdx.x * blockDim.x + threadIdx.x;
    if (i < E) atomicAdd(&deg[ei[E + i]], 1);
    else if (i < E + N) atomicAdd(&deg[i - E], 1);
}

__global__ __launch_bounds__(256) void scan_pass1(const int* __restrict__ deg, int* __restrict__ rowptr,
                                                  int* __restrict__ bsum, int N) {
    __shared__ int sd[256];
    int t = threadIdx.x, i = blockIdx.x * 256 + t;
    int d = (i < N) ? deg[i] : 0;
    sd[t] = d;
    __syncthreads();
    for (int off = 1; off < 256; off <<= 1) {
        int v = (t >= off) ? sd[t - off] : 0;
        __syncthreads();
        sd[t] += v;
        __syncthreads();
    }
    if (i < N) rowptr[i] = sd[t] - d;
    if (t == 255) bsum[blockIdx.x] = sd[t];
}

__global__ __launch_bounds__(128) void scan_pass2(const int* __restrict__ bsum, int* __restrict__ boff,
                                                  int* __restrict__ rowptr, int nb, int N) {
    __shared__ int sd[128];
    int t = threadIdx.x;
    int d = (t < nb) ? bsum[t] : 0;
    sd[t] = d;
    __syncthreads();
    for (int off = 1; off < 128; off <<= 1) {
        int v = (t >= off) ? sd[t - off] : 0;
        __syncthreads();
        sd[t] += v;
        __syncthreads();
    }
    if (t < nb) boff[t] = sd[t] - d;
    if (t == 127) rowptr[N] = sd[t];
}

__global__ __launch_bounds__(256) void scan_pass3(int* __restrict__ rowptr, const int* __restrict__ boff, int N) {
    int i = blockIdx.x * 256 + threadIdx.x;
    if (i < N) rowptr[i] += boff[blockIdx.x];
}

__global__ void scatter_kernel(const int* __restrict__ ei, int E, int N,
                               const int* __restrict__ rowptr, int* __restrict__ cursor,
                               int* __restrict__ esrc, int* __restrict__ edst) {
    int i = blockIdx.x * blockDim.x + threadIdx.x;
    int s, d;
    if (i < E) { s = ei[i]; d = ei[E + i]; }
    else if (i < E + N) { s = i - E; d = s; }
    else return;
    int pos = rowptr[d] + atomicAdd(&cursor[d], 1);
    esrc[pos] = s;
    edst[pos] = d;
}

// ---------------- per-edge logits (CSR order) ---------------------------------
__global__ void edge_e1_kernel(const int* __restrict__ esrc, const int* __restrict__ edst,
                               const float4* __restrict__ as4, const float4* __restrict__ ad4,
                               float4* __restrict__ eb, int Etot) {
    int i = blockIdx.x * blockDim.x + threadIdx.x;
    if (i >= Etot) return;
    float4 u = as4[esrc[i]];
    float4 v = ad4[edst[i]];
    float4 e;
    e.x = LRELU(u.x + v.x); e.y = LRELU(u.y + v.y);
    e.z = LRELU(u.z + v.z); e.w = LRELU(u.w + v.w);
    eb[i] = e;
}

__global__ void edge_e2_kernel(const int* __restrict__ esrc, const int* __restrict__ edst,
                               const float* __restrict__ as, const float* __restrict__ ad,
                               float* __restrict__ eb, int Etot) {
    int i = blockIdx.x * blockDim.x + threadIdx.x;
    if (i >= Etot) return;
    float e = as[esrc[i]] + ad[edst[i]];
    eb[i] = LRELU(e);
}

// ---------------- prep: x->bf16 + 3 weight transposes (one dispatch) ----------
__global__ void prep_kernel(const float* __restrict__ x, const float* __restrict__ We,
                            const float* __restrict__ W1, const float* __restrict__ W2,
                            unsigned short* __restrict__ xb, unsigned short* __restrict__ WeT,
                            unsigned short* __restrict__ W1T, unsigned short* __restrict__ W2T,
                            int Nx) {
    int i = blockIdx.x * blockDim.x + threadIdx.x;
    if (i < Nx) { xb[i] = f2b(x[i]); return; }
    i -= Nx;
    if (i < 64 * 128) { int k = i >> 7, n = i & 127; WeT[n * 64 + k] = f2b(We[i]); return; }
    i -= 64 * 128;
    if (i < 128 * 512) { int k = i >> 9, n = i & 511; W1T[n * 128 + k] = f2b(W1[i]); return; }
    i -= 128 * 512;
    if (i < 512 * 128) { int k = i >> 7, n = i & 127; W2T[n * 512 + k] = f2b(W2[i]); return; }
}

// ---------------- MFMA bf16 NT GEMM: C[M,N] = A[M,K] @ Bt[N,K]^T --------------
template <int ACT>
__global__ __launch_bounds__(256) void gemm_mfma_nt(const unsigned short* __restrict__ A,
                                                    const unsigned short* __restrict__ Bt,
                                                    const float* __restrict__ bias,
                                                    unsigned short* __restrict__ C,
                                                    int M, int N, int K) {
    __shared__ __align__(16) unsigned short As[128 * 40];
    __shared__ __align__(16) unsigned short Bs[128 * 40];
    int tid = threadIdx.x;
    int gm0 = blockIdx.y * 128, gn0 = blockIdx.x * 128;
    int w = tid >> 6, lane = tid & 63;
    int wrow = (w >> 1) * 64, wcol = (w & 1) * 64;
    int l15 = lane & 15, quad = lane >> 4;

    f32x4 acc[4][4];
#pragma unroll
    for (int i = 0; i < 4; i++)
#pragma unroll
        for (int j = 0; j < 4; j++) acc[i][j] = {0.f, 0.f, 0.f, 0.f};

    for (int k0 = 0; k0 < K; k0 += 32) {
#pragma unroll
        for (int rr = 0; rr < 2; rr++) {
            int lin = tid + rr * 256;
            int row = lin >> 2;
            int cg = (lin & 3) * 8;
            int grow = gm0 + row; if (grow >= M) grow = M - 1;
            uint4 va = *(const uint4*)&A[(size_t)grow * K + k0 + cg];
            *(uint4*)&As[row * 40 + cg] = va;
            uint4 vb = *(const uint4*)&Bt[(size_t)(gn0 + row) * K + k0 + cg];
            *(uint4*)&Bs[row * 40 + cg] = vb;
        }
        __syncthreads();
        bf16x8 af[4], bfr[4];
#pragma unroll
        for (int i = 0; i < 4; i++) {
            af[i]  = *(const bf16x8*)&As[(wrow + i * 16 + l15) * 40 + quad * 8];
            bfr[i] = *(const bf16x8*)&Bs[(wcol + i * 16 + l15) * 40 + quad * 8];
        }
#pragma unroll
        for (int i = 0; i < 4; i++)
#pragma unroll
            for (int j = 0; j < 4; j++)
                acc[i][j] = __builtin_amdgcn_mfma_f32_16x16x32_bf16(af[i], bfr[j], acc[i][j], 0, 0, 0);
        __syncthreads();
    }

#pragma unroll
    for (int i = 0; i < 4; i++) {
        int row = gm0 + wrow + i * 16 + quad * 4;
#pragma unroll
        for (int j = 0; j < 4; j++) {
            int col = gn0 + wcol + j * 16 + l15;
            float bv = bias ? bias[col] : 0.f;
#pragma unroll
            for (int r = 0; r < 4; r++) {
                int gr = row + r;
                if (gr < M) {
                    float v = acc[i][j][r] + bv;
                    if (ACT == 1) v = fmaxf(v, 0.f);
                    C[(size_t)gr * N + col] = f2b(v);
                }
            }
        }
    }
}

// ---------------- alpha: one wave per node, bf16 row, shuffle reduce ----------
template <int H>
__global__ __launch_bounds__(256) void alpha_wave_kernel(const unsigned short* __restrict__ hb,
                                                         const float* __restrict__ a_src,
                                                         const float* __restrict__ a_dst,
                                                         float* __restrict__ as_out,
                                                         float* __restrict__ ad_out, int N) {
    int wid = (blockIdx.x * 256 + threadIdx.x) >> 6;
    int lane = threadIdx.x & 63;
    if (wid >= N) return;
    const int F = H * 128;
    float ds = 0.f, dd = 0.f;
    if (lane * 8 < F) {
        uint4 v = *(const uint4*)&hb[(size_t)wid * F + lane * 8];
        unsigned uu[4] = {v.x, v.y, v.z, v.w};
#pragma unroll
        for (int t = 0; t < 4; t++) {
            float f0 = blo(uu[t]), f1 = bhi(uu[t]);
            int c = lane * 8 + 2 * t;
            ds += f0 * a_src[c] + f1 * a_src[c + 1];
            dd += f0 * a_dst[c] + f1 * a_dst[c + 1];
        }
    }
#pragma unroll
    for (int o = 1; o < 16; o <<= 1) {
        ds += __shfl_xor(ds, o);
        dd += __shfl_xor(dd, o);
    }
    if ((lane & 15) == 0) {
        int h = lane >> 4;
        if (h < H) {
            as_out[wid * H + h] = ds;
            ad_out[wid * H + h] = dd;
        }
    }
}

// ---------------- GAT agg L1 (H=4): 1 wave/node, 4-edge unroll ----------------
__global__ __launch_bounds__(256) void gat_agg_l1(const unsigned short* __restrict__ hpre,
                                                  const float4* __restrict__ eb4,
                                                  const int* __restrict__ rowptr,
                                                  const int* __restrict__ esrc,
                                                  const float* __restrict__ bias,
                                                  unsigned short* __restrict__ out, int N) {
    __shared__ float wlds_all[4][256];
    int w = threadIdx.x >> 6, lane = threadIdx.x & 63;
    int n = blockIdx.x * 4 + w;
    if (n >= N) return;
    float* wlds = wlds_all[w];
    int begin = rowptr[n], end = rowptr[n + 1];
    int deg = end - begin;

    // pass 1: per-head max (contiguous 16B reads)
    float4 m = {-3.4e38f, -3.4e38f, -3.4e38f, -3.4e38f};
    for (int base = 0; base < deg; base += 64) {
        int j = base + lane;
        if (j < deg) {
            float4 e = eb4[begin + j];
            m.x = fmaxf(m.x, e.x); m.y = fmaxf(m.y, e.y);
            m.z = fmaxf(m.z, e.z); m.w = fmaxf(m.w, e.w);
        }
    }
#pragma unroll
    for (int o = 32; o >= 1; o >>= 1) {
        m.x = fmaxf(m.x, __shfl_xor(m.x, o));
        m.y = fmaxf(m.y, __shfl_xor(m.y, o));
        m.z = fmaxf(m.z, __shfl_xor(m.z, o));
        m.w = fmaxf(m.w, __shfl_xor(m.w, o));
    }
    // pass 2: per-head sum of exp
    float4 s4 = {0.f, 0.f, 0.f, 0.f};
    for (int base = 0; base < deg; base += 64) {
        int j = base + lane;
        if (j < deg) {
            float4 e = eb4[begin + j];
            s4.x += __expf(e.x - m.x); s4.y += __expf(e.y - m.y);
            s4.z += __expf(e.z - m.z); s4.w += __expf(e.w - m.w);
        }
    }
#pragma unroll
    for (int o = 32; o >= 1; o >>= 1) {
        s4.x += __shfl_xor(s4.x, o); s4.y += __shfl_xor(s4.y, o);
        s4.z += __shfl_xor(s4.z, o); s4.w += __shfl_xor(s4.w, o);
    }
    float4 inv = {1.f / (s4.x + 1e-16f), 1.f / (s4.y + 1e-16f),
                  1.f / (s4.z + 1e-16f), 1.f / (s4.w + 1e-16f)};

    // pass 3: weighted gather, 4-edge unroll (4 independent 16B loads in flight)
    float acc[8] = {};
    int h = lane >> 4;
    for (int base = 0; base < deg; base += 64) {
        int j = base + lane;
        int len = min(64, deg - base);
        int s_l = 0;
        if (j < deg) {
            s_l = esrc[begin + j];
            float4 e = eb4[begin + j];
            float4 wv4;
            wv4.x = __expf(e.x - m.x) * inv.x;
            wv4.y = __expf(e.y - m.y) * inv.y;
            wv4.z = __expf(e.z - m.z) * inv.z;
            wv4.w = __expf(e.w - m.w) * inv.w;
            *(float4*)&wlds[lane * 4] = wv4;   // wave-private: no barrier needed
        }
        int c = 0;
        for (; c + 4 <= len; c += 4) {
            int s0 = __builtin_amdgcn_readlane(s_l, c);
            int s1 = __builtin_amdgcn_readlane(s_l, c + 1);
            int s2 = __builtin_amdgcn_readlane(s_l, c + 2);
            int s3 = __builtin_amdgcn_readlane(s_l, c + 3);
            uint4 h0 = *((const uint4*)(hpre + ((size_t)s0 << 9)) + lane);
            uint4 h1 = *((const uint4*)(hpre + ((size_t)s1 << 9)) + lane);
            uint4 h2 = *((const uint4*)(hpre + ((size_t)s2 << 9)) + lane);
            uint4 h3 = *((const uint4*)(hpre + ((size_t)s3 << 9)) + lane);
            float w0 = wlds[c * 4 + h];
            float w1 = wlds[c * 4 + 4 + h];
            float w2 = wlds[c * 4 + 8 + h];
            float w3 = wlds[c * 4 + 12 + h];
            acc[0] += w0 * blo(h0.x); acc[1] += w0 * bhi(h0.x);
            acc[2] += w0 * blo(h0.y); acc[3] += w0 * bhi(h0.y);
            acc[4] += w0 * blo(h0.z); acc[5] += w0 * bhi(h0.z);
            acc[6] += w0 * blo(h0.w); acc[7] += w0 * bhi(h0.w);
            acc[0] += w1 * blo(h1.x); acc[1] += w1 * bhi(h1.x);
            acc[2] += w1 * blo(h1.y); acc[3] += w1 * bhi(h1.y);
            acc[4] += w1 * blo(h1.z); acc[5] += w1 * bhi(h1.z);
            acc[6] += w1 * blo(h1.w); acc[7] += w1 * bhi(h1.w);
            acc[0] += w2 * blo(h2.x); acc[1] += w2 * bhi(h2.x);
            acc[2] += w2 * blo(h2.y); acc[3] += w2 * bhi(h2.y);
            acc[4] += w2 * blo(h2.z); acc[5] += w2 * bhi(h2.z);
            acc[6] += w2 * blo(h2.w); acc[7] += w2 * bhi(h2.w);
            acc[0] += w3 * blo(h3.x); acc[1] += w3 * bhi(h3.x);
            acc[2] += w3 * blo(h3.y); acc[3] += w3 * bhi(h3.y);
            acc[4] += w3 * blo(h3.z); acc[5] += w3 * bhi(h3.z);
            acc[6] += w3 * blo(h3.w); acc[7] += w3 * bhi(h3.w);
        }
        for (; c < len; c++) {
            int s0 = __builtin_amdgcn_readlane(s_l, c);
            uint4 h0 = *((const uint4*)(hpre + ((size_t)s0 << 9)) + lane);
            float w0 = wlds[c * 4 + h];
            acc[0] += w0 * blo(h0.x); acc[1] += w0 * bhi(h0.x);
            acc[2] += w0 * blo(h0.y); acc[3] += w0 * bhi(h0.y);
            acc[4] += w0 * blo(h0.z); acc[5] += w0 * bhi(h0.z);
            acc[6] += w0 * blo(h0.w); acc[7] += w0 * bhi(h0.w);
        }
    }
    // epilogue: bias + ELU + pack bf16x8 -> one 16B store
    int f0 = lane * 8;
    unsigned pk[4];
#pragma unroll
    for (int k = 0; k < 4; k++) {
        float v0 = acc[2 * k] + bias[f0 + 2 * k];
        float v1 = acc[2 * k + 1] + bias[f0 + 2 * k + 1];
        v0 = v0 > 0.f ? v0 : (__expf(v0) - 1.f);
        v1 = v1 > 0.f ? v1 : (__expf(v1) - 1.f);
        pk[k] = (unsigned)f2b(v0) | ((unsigned)f2b(v1) << 16);
    }
    uint4 pv = {pk[0], pk[1], pk[2], pk[3]};
    *((uint4*)(out + (size_t)n * 512) + lane) = pv;
}

// ---------------- GAT agg L2 (H=1): 1 wave/node, 4-edge unroll ----------------
__global__ __launch_bounds__(256) void gat_agg_l2(const unsigned short* __restrict__ hpre,
                                                  const float* __restrict__ eb,
                                                  const int* __restrict__ rowptr,
                                                  const int* __restrict__ esrc,
                                                  const float* __restrict__ bias,
                                                  float* __restrict__ out, int N) {
    int w = threadIdx.x >> 6, lane = threadIdx.x & 63;
    int n = blockIdx.x * 4 + w;
    if (n >= N) return;
    int begin = rowptr[n], end = rowptr[n + 1];
    int deg = end - begin;

    float m = -3.4e38f;
    for (int base = 0; base < deg; base += 64) {
        int j = base + lane;
        if (j < deg) m = fmaxf(m, eb[begin + j]);
    }
#pragma unroll
    for (int o = 32; o >= 1; o >>= 1) m = fmaxf(m, __shfl_xor(m, o));

    float s = 0.f;
    for (int base = 0; base < deg; base += 64) {
        int j = base + lane;
        if (j < deg) s += __expf(eb[begin + j] - m);
    }
#pragma unroll
    for (int o = 32; o >= 1; o >>= 1) s += __shfl_xor(s, o);
    float inv = 1.f / (s + 1e-16f);

    float acc0 = 0.f, acc1 = 0.f;
    for (int base = 0; base < deg; base += 64) {
        int j = base + lane;
        int len = min(64, deg - base);
        int s_l = 0; float w_l = 0.f;
        if (j < deg) {
            s_l = esrc[begin + j];
            w_l = __expf(eb[begin + j] - m) * inv;
        }
        int c = 0;
        for (; c + 4 <= len; c += 4) {
            int sp0 = __builtin_amdgcn_readlane(s_l, c);
            int sp1 = __builtin_amdgcn_readlane(s_l, c + 1);
            int sp2 = __builtin_amdgcn_readlane(s_l, c + 2);
            int sp3 = __builtin_amdgcn_readlane(s_l, c + 3);
            unsigned u0 = *((const unsigned*)(hpre + ((size_t)sp0 << 7)) + lane);
            unsigned u1 = *((const unsigned*)(hpre + ((size_t)sp1 << 7)) + lane);
            unsigned u2 = *((const unsigned*)(hpre + ((size_t)sp2 << 7)) + lane);
            unsigned u3 = *((const unsigned*)(hpre + ((size_t)sp3 << 7)) + lane);
            float w0 = rl_f(w_l, c), w1 = rl_f(w_l, c + 1);
            float w2 = rl_f(w_l, c + 2), w3 = rl_f(w_l, c + 3);
            acc0 += w0 * blo(u0); acc1 += w0 * bhi(u0);
            acc0 += w1 * blo(u1); acc1 += w1 * bhi(u1);
            acc0 += w2 * blo(u2); acc1 += w2 * bhi(u2);
            acc0 += w3 * blo(u3); acc1 += w3 * bhi(u3);
        }
        for (; c < len; c++) {
            int sp0 = __builtin_amdgcn_readlane(s_l, c);
            float w0 = rl_f(w_l, c);
            unsigned u0 = *((const unsigned*)(hpre + ((size_t)sp0 << 7)) + lane);
            acc0 += w0 * blo(u0); acc1 += w0 * bhi(u0);
        }
    }
    float v0 = acc0 + bias[lane * 2];
    float v1 = acc1 + bias[lane * 2 + 1];
    v0 = v0 > 0.f ? v0 : (__expf(v0) - 1.f);
    v1 = v1 > 0.f ? v1 : (__expf(v1) - 1.f);
    float2 pv = {v0, v1};
    *(float2*)&out[(size_t)n * 128 + lane * 2] = pv;
}

// ---------------- mean pool + final GEMV (fused via done-counter) -------------
__global__ __launch_bounds__(256) void pool_final_kernel(const float* __restrict__ o2,
                                                         float* __restrict__ pool,
                                                         int* __restrict__ done,
                                                         const float* __restrict__ Wout,
                                                         const float* __restrict__ bout,
                                                         float* __restrict__ out,
                                                         int N, int nblocks, float invN) {
    __shared__ float4 sred[256];
    int f4 = threadIdx.x & 31;
    int r = blockIdx.x * 256 + (threadIdx.x >> 5);
    float4 acc = {0.f, 0.f, 0.f, 0.f};
    for (int i = 0; i < 32; i++, r += 8) {
        if (r < N) {
            float4 v = *(const float4*)&o2[(size_t)r * 128 + f4 * 4];
            acc.x += v.x; acc.y += v.y; acc.z += v.z; acc.w += v.w;
        }
    }
    sred[threadIdx.x] = acc;
    __syncthreads();
    if (threadIdx.x < 32) {
        float4 t = sred[threadIdx.x];
#pragma unroll
        for (int k = 1; k < 8; k++) {
            float4 u = sred[threadIdx.x + 32 * k];
            t.x += u.x; t.y += u.y; t.z += u.z; t.w += u.w;
        }
        atomicAdd(&pool[f4 * 4 + 0], t.x);
        atomicAdd(&pool[f4 * 4 + 1], t.y);
        atomicAdd(&pool[f4 * 4 + 2], t.z);
        atomicAdd(&pool[f4 * 4 + 3], t.w);
    }
    __threadfence();
    __shared__ int isLast;
    if (threadIdx.x == 0) isLast = (atomicAdd(done, 1) == nblocks - 1);
    __syncthreads();
    if (isLast) {
        __shared__ float spool[128];
        if (threadIdx.x < 128) spool[threadIdx.x] = atomicAdd(&pool[threadIdx.x], 0.f);
        __syncthreads();
        int o = threadIdx.x;
        float a = 0.f;
        for (int k = 0; k < 128; k++) a += spool[k] * Wout[k * 256 + o];
        out[o] = a * invN + bout[o];
    }
}

// ---------------- launch ------------------------------------------------------
extern "C" void kernel_launch(void* const* d_in, const int* in_sizes, int n_in,
                              void* d_out, int out_size, void* d_ws, size_t ws_size,
                              hipStream_t stream) {
    const float* x      = (const float*)d_in[0];
    const int*   ei     = (const int*)d_in[1];
    const float* W_emb  = (const float*)d_in[2];
    const float* b_emb  = (const float*)d_in[3];
    const float* W1     = (const float*)d_in[4];
    const float* a1_src = (const float*)d_in[5];
    const float* a1_dst = (const float*)d_in[6];
    const float* b1     = (const float*)d_in[7];
    const float* W2     = (const float*)d_in[8];
    const float* a2_src = (const float*)d_in[9];
    const float* a2_dst = (const float*)d_in[10];
    const float* b2     = (const float*)d_in[11];
    const float* W_out  = (const float*)d_in[12];
    const float* b_out  = (const float*)d_in[13];
    float* out = (float*)d_out;

    const int N = in_sizes[0] / 64;   // 25000
    const int E = in_sizes[1] / 2;    // 400000
    const int Etot = E + N;
    const int nb = (N + 255) / 256;

    char* ws = (char*)d_ws;
    size_t off = 0;
    auto alloc = [&](size_t bytes) -> void* {
        void* p = ws + off;
        off = (off + bytes + 255) & ~(size_t)255;
        return p;
    };
    typedef unsigned short u16;
    u16* xb    = (u16*)alloc((size_t)N * 64 * 2);
    u16* WeT   = (u16*)alloc((size_t)128 * 64 * 2);
    u16* W1T   = (u16*)alloc((size_t)512 * 128 * 2);
    u16* W2T   = (u16*)alloc((size_t)128 * 512 * 2);
    u16* h0b   = (u16*)alloc((size_t)N * 128 * 2);
    u16* h1b   = (u16*)alloc((size_t)N * 512 * 2);
    u16* o1b   = (u16*)alloc((size_t)N * 512 * 2);
    u16* h2b   = (u16*)alloc((size_t)N * 128 * 2);
    float* o2  = (float*)alloc((size_t)N * 128 * 4);
    float* as1 = (float*)alloc((size_t)N * 4 * 4);
    float* ad1 = (float*)alloc((size_t)N * 4 * 4);
    float* as2 = (float*)alloc((size_t)N * 4);
    float* ad2 = (float*)alloc((size_t)N * 4);
    float* pool = (float*)alloc(128 * 4);
    int* done   = (int*)alloc(256);
    int* rowptr = (int*)alloc((size_t)(N + 1) * 4);
    int* deg    = (int*)alloc((size_t)N * 4);
    int* cursor = (int*)alloc((size_t)N * 4);
    int* bsum   = (int*)alloc(128 * 4);
    int* boff   = (int*)alloc(128 * 4);
    int* esrc   = (int*)alloc((size_t)Etot * 4);
    int* edst   = (int*)alloc((size_t)Etot * 4);
    float* eb1  = (float*)alloc((size_t)Etot * 4 * 4);
    float* eb2  = (float*)alloc((size_t)Etot * 4);

    // zero scratch + CSR build (small kernels — grid.sync fusion measured 6x slower)
    zero_kernel<<<(2 * N + 129 + 255) / 256, 256, 0, stream>>>(deg, cursor, pool, done, N);
    int blocksE = (Etot + 255) / 256;
    deg_count_kernel<<<blocksE, 256, 0, stream>>>(ei, E, N, deg);
    scan_pass1<<<nb, 256, 0, stream>>>(deg, rowptr, bsum, N);
    scan_pass2<<<1, 128, 0, stream>>>(bsum, boff, rowptr, nb, N);
    scan_pass3<<<nb, 256, 0, stream>>>(rowptr, boff, N);
    scatter_kernel<<<blocksE, 256, 0, stream>>>(ei, E, N, rowptr, cursor, esrc, edst);

    // bf16 conversions + weight transposes (single dispatch)
    int Nx = N * 64;
    int prep_elems = Nx + 64 * 128 + 128 * 512 + 512 * 128;
    prep_kernel<<<(prep_elems + 255) / 256, 256, 0, stream>>>(x, W_emb, W1, W2, xb, WeT, W1T, W2T, Nx);

    int mtiles = (N + 127) / 128;
    gemm_mfma_nt<1><<<dim3(1, mtiles), 256, 0, stream>>>(xb, WeT, b_emb, h0b, N, 128, 64);
    gemm_mfma_nt<0><<<dim3(4, mtiles), 256, 0, stream>>>(h0b, W1T, nullptr, h1b, N, 512, 128);

    // layer-1 attention + aggregation
    alpha_wave_kernel<4><<<(N * 64 + 255) / 256, 256, 0, stream>>>(h1b, a1_src, a1_dst, as1, ad1, N);
    edge_e1_kernel<<<blocksE, 256, 0, stream>>>(esrc, edst, (const float4*)as1, (const float4*)ad1,
                                                (float4*)eb1, Etot);
    gat_agg_l1<<<(N + 3) / 4, 256, 0, stream>>>(h1b, (const float4*)eb1, rowptr, esrc, b1, o1b, N);

    gemm_mfma_nt<0><<<dim3(1, mtiles), 256, 0, stream>>>(o1b, W2T, nullptr, h2b, N, 128, 512);

    // layer-2 attention + aggregation
    alpha_wave_kernel<1><<<(N * 64 + 255) / 256, 256, 0, stream>>>(h2b, a2_src, a2_dst, as2, ad2, N);
    edge_e2_kernel<<<blocksE, 256, 0, stream>>>(esrc, edst, as2, ad2, eb2, Etot);
    gat_agg_l2<<<(N + 3) / 4, 256, 0, stream>>>(h2b, eb2, rowptr, esrc, b2, o2, N);

    // mean pool + final GEMV (one dispatch)
    int npb = (N + 255) / 256;
    pool_final_kernel<<<npb, 256, 0, stream>>>(o2, pool, done, W_out, b_out, out,
                                               N, npb, 1.f / (float)N);
}

// Round 7
// 280.498 us; speedup vs baseline: 1.8056x; 1.1763x over previous
//
#include <hip/hip_runtime.h>
#include <hip/hip_bf16.h>

// N=25000, E=400000 (+N self loops), F_IN=64, HID=128, HEADS=4, OUT=256
// Interior: bf16 MFMA GEMMs; node-feature gather operands stored fp8(e4m3);
// alpha dot-products fused into GEMM epilogues (f32-exact); edge logits
// computed on the fly in agg kernels from L2-resident alpha tables.
// NOTE: cooperative grid.sync measured ~30us/barrier on gfx950 — never use it
// to fuse cheap kernels (round-5 regression: 6-barrier CSR build = 180us).

#define LRELU(x) ((x) > 0.f ? (x) : 0.2f * (x))

typedef short bf16x8 __attribute__((ext_vector_type(8)));
typedef float f32x4 __attribute__((ext_vector_type(4)));
typedef float f32x2 __attribute__((ext_vector_type(2)));

static __device__ __forceinline__ unsigned short f2b(float f) {
    union { float f; unsigned u; } x; x.f = f;
    unsigned r = x.u + 0x7fff + ((x.u >> 16) & 1);
    return (unsigned short)(r >> 16);
}
static __device__ __forceinline__ float rl_f(float v, int c) {
    return __int_as_float(__builtin_amdgcn_readlane(__float_as_int(v), c));
}
static __device__ __forceinline__ unsigned char f2fp8(float v) {
    int p = __builtin_amdgcn_cvt_pk_fp8_f32(v, v, 0, false);
    return (unsigned char)(p & 0xff);
}

// ---------------- zero scratch ------------------------------------------------
__global__ void zero_kernel(int* __restrict__ deg, int* __restrict__ cursor,
                            float* __restrict__ pool, int* __restrict__ done, int N) {
    int i = blockIdx.x * blockDim.x + threadIdx.x;
    if (i < N) deg[i] = 0;
    else if (i < 2 * N) cursor[i - N] = 0;
    else if (i < 2 * N + 128) pool[i - 2 * N] = 0.f;
    else if (i == 2 * N + 128) *done = 0;
}

// ---------------- CSR build (6 small kernels — proven fast) -------------------
__global__ void deg_count_kernel(const int* __restrict__ ei, int E, int N, int* __restrict__ deg) {
    int i = blockIdx.x * blockDim.x + threadIdx.x;
    if (i < E) atomicAdd(&deg[ei[E + i]], 1);
    else if (i < E + N) atomicAdd(&deg[i - E], 1);
}

__global__ __launch_bounds__(256) void scan_pass1(const int* __restrict__ deg, int* __restrict__ rowptr,
                                                  int* __restrict__ bsum, int N) {
    __shared__ int sd[256];
    int t = threadIdx.x, i = blockIdx.x * 256 + t;
    int d = (i < N) ? deg[i] : 0;
    sd[t] = d;
    __syncthreads();
    for (int off = 1; off < 256; off <<= 1) {
        int v = (t >= off) ? sd[t - off] : 0;
        __syncthreads();
        sd[t] += v;
        __syncthreads();
    }
    if (i < N) rowptr[i] = sd[t] - d;
    if (t == 255) bsum[blockIdx.x] = sd[t];
}

__global__ __launch_bounds__(128) void scan_pass2(const int* __restrict__ bsum, int* __restrict__ boff,
                                                  int* __restrict__ rowptr, int nb, int N) {
    __shared__ int sd[128];
    int t = threadIdx.x;
    int d = (t < nb) ? bsum[t] : 0;
    sd[t] = d;
    __syncthreads();
    for (int off = 1; off < 128; off <<= 1) {
        int v = (t >= off) ? sd[t - off] : 0;
        __syncthreads();
        sd[t] += v;
        __syncthreads();
    }
    if (t < nb) boff[t] = sd[t] - d;
    if (t == 127) rowptr[N] = sd[t];
}

__global__ __launch_bounds__(256) void scan_pass3(int* __restrict__ rowptr, const int* __restrict__ boff, int N) {
    int i = blockIdx.x * 256 + threadIdx.x;
    if (i < N) rowptr[i] += boff[blockIdx.x];
}

__global__ void scatter_kernel(const int* __restrict__ ei, int E, int N,
                               const int* __restrict__ rowptr, int* __restrict__ cursor,
                               int* __restrict__ esrc) {
    int i = blockIdx.x * blockDim.x + threadIdx.x;
    int s, d;
    if (i < E) { s = ei[i]; d = ei[E + i]; }
    else if (i < E + N) { s = i - E; d = s; }
    else return;
    int pos = rowptr[d] + atomicAdd(&cursor[d], 1);
    esrc[pos] = s;
}

// ---------------- prep: x->bf16 + 3 weight transposes (one dispatch) ----------
__global__ void prep_kernel(const float* __restrict__ x, const float* __restrict__ We,
                            const float* __restrict__ W1, const float* __restrict__ W2,
                            unsigned short* __restrict__ xb, unsigned short* __restrict__ WeT,
                            unsigned short* __restrict__ W1T, unsigned short* __restrict__ W2T,
                            int Nx) {
    int i = blockIdx.x * blockDim.x + threadIdx.x;
    if (i < Nx) { xb[i] = f2b(x[i]); return; }
    i -= Nx;
    if (i < 64 * 128) { int k = i >> 7, n = i & 127; WeT[n * 64 + k] = f2b(We[i]); return; }
    i -= 64 * 128;
    if (i < 128 * 512) { int k = i >> 9, n = i & 511; W1T[n * 128 + k] = f2b(W1[i]); return; }
    i -= 128 * 512;
    if (i < 512 * 128) { int k = i >> 7, n = i & 127; W2T[n * 512 + k] = f2b(W2[i]); return; }
}

// ---------------- MFMA bf16 NT GEMM: C[M,N] = A[M,K] @ Bt[N,K]^T --------------
// OFMT: 0 = bf16 out (+bias, +relu if ACT), 1 = fp8 e4m3 out (no bias/act).
// ALPHA: fuse alpha_src/alpha_dst dot products (col-tile == head hh=blockIdx.x).
template <int ACT, int OFMT, int ALPHA, int H>
__global__ __launch_bounds__(256) void gemm_mfma_nt(const unsigned short* __restrict__ A,
                                                    const unsigned short* __restrict__ Bt,
                                                    const float* __restrict__ bias,
                                                    void* __restrict__ Cout,
                                                    const float* __restrict__ a_src,
                                                    const float* __restrict__ a_dst,
                                                    float* __restrict__ as_out,
                                                    float* __restrict__ ad_out,
                                                    int M, int N, int K) {
    __shared__ __align__(16) unsigned short As[128 * 40];
    __shared__ __align__(16) unsigned short Bs[128 * 40];
    __shared__ float sAl[128][2];
    int tid = threadIdx.x;
    int gm0 = blockIdx.y * 128, gn0 = blockIdx.x * 128;
    int w = tid >> 6, lane = tid & 63;
    int wrow = (w >> 1) * 64, wcol = (w & 1) * 64;
    int l15 = lane & 15, quad = lane >> 4;

    f32x4 acc[4][4];
#pragma unroll
    for (int i = 0; i < 4; i++)
#pragma unroll
        for (int j = 0; j < 4; j++) acc[i][j] = {0.f, 0.f, 0.f, 0.f};

    for (int k0 = 0; k0 < K; k0 += 32) {
#pragma unroll
        for (int rr = 0; rr < 2; rr++) {
            int lin = tid + rr * 256;
            int row = lin >> 2;
            int cg = (lin & 3) * 8;
            int grow = gm0 + row; if (grow >= M) grow = M - 1;
            uint4 va = *(const uint4*)&A[(size_t)grow * K + k0 + cg];
            *(uint4*)&As[row * 40 + cg] = va;
            uint4 vb = *(const uint4*)&Bt[(size_t)(gn0 + row) * K + k0 + cg];
            *(uint4*)&Bs[row * 40 + cg] = vb;
        }
        __syncthreads();
        bf16x8 af[4], bfr[4];
#pragma unroll
        for (int i = 0; i < 4; i++) {
            af[i]  = *(const bf16x8*)&As[(wrow + i * 16 + l15) * 40 + quad * 8];
            bfr[i] = *(const bf16x8*)&Bs[(wcol + i * 16 + l15) * 40 + quad * 8];
        }
#pragma unroll
        for (int i = 0; i < 4; i++)
#pragma unroll
            for (int j = 0; j < 4; j++)
                acc[i][j] = __builtin_amdgcn_mfma_f32_16x16x32_bf16(af[i], bfr[j], acc[i][j], 0, 0, 0);
        __syncthreads();
    }

    // ---- store ----
    if (OFMT == 0) {
        unsigned short* C = (unsigned short*)Cout;
#pragma unroll
        for (int i = 0; i < 4; i++) {
            int row = gm0 + wrow + i * 16 + quad * 4;
#pragma unroll
            for (int j = 0; j < 4; j++) {
                int col = gn0 + wcol + j * 16 + l15;
                float bv = bias ? bias[col] : 0.f;
#pragma unroll
                for (int r = 0; r < 4; r++) {
                    int gr = row + r;
                    if (gr < M) {
                        float v = acc[i][j][r] + bv;
                        if (ACT == 1) v = fmaxf(v, 0.f);
                        C[(size_t)gr * N + col] = f2b(v);
                    }
                }
            }
        }
    } else {
        unsigned char* C8 = (unsigned char*)Cout;
#pragma unroll
        for (int i = 0; i < 4; i++) {
            int row = gm0 + wrow + i * 16 + quad * 4;
#pragma unroll
            for (int j = 0; j < 4; j++) {
                int col = gn0 + wcol + j * 16 + l15;
#pragma unroll
                for (int r = 0; r < 4; r++) {
                    int gr = row + r;
                    if (gr < M) C8[(size_t)gr * N + col] = f2fp8(acc[i][j][r]);
                }
            }
        }
    }

    // ---- fused alpha: per-row dot with a_src/a_dst over this col-tile -------
    if (ALPHA) {
        int hh = blockIdx.x;
        float as_c[4], ad_c[4];
#pragma unroll
        for (int j = 0; j < 4; j++) {
            int c = gn0 + wcol + j * 16 + l15;   // gn0 == hh*128
            as_c[j] = a_src[c];
            ad_c[j] = a_dst[c];
        }
        // phase 1: cols-64..127 waves deposit row partials into LDS
#pragma unroll
        for (int i = 0; i < 4; i++) {
#pragma unroll
            for (int r = 0; r < 4; r++) {
                float ps = 0.f, pd = 0.f;
#pragma unroll
                for (int j = 0; j < 4; j++) {
                    ps += acc[i][j][r] * as_c[j];
                    pd += acc[i][j][r] * ad_c[j];
                }
#pragma unroll
                for (int o = 1; o < 16; o <<= 1) {
                    ps += __shfl_xor(ps, o);
                    pd += __shfl_xor(pd, o);
                }
                if (wcol == 64 && l15 == 0) {
                    int lr = wrow + i * 16 + quad * 4 + r;
                    sAl[lr][0] = ps;
                    sAl[lr][1] = pd;
                }
            }
        }
        __syncthreads();
        // phase 2: cols-0..63 waves combine and write
        if (wcol == 0) {
#pragma unroll
            for (int i = 0; i < 4; i++) {
#pragma unroll
                for (int r = 0; r < 4; r++) {
                    float ps = 0.f, pd = 0.f;
#pragma unroll
                    for (int j = 0; j < 4; j++) {
                        ps += acc[i][j][r] * as_c[j];
                        pd += acc[i][j][r] * ad_c[j];
                    }
#pragma unroll
                    for (int o = 1; o < 16; o <<= 1) {
                        ps += __shfl_xor(ps, o);
                        pd += __shfl_xor(pd, o);
                    }
                    if (l15 == 0) {
                        int lr = wrow + i * 16 + quad * 4 + r;
                        int gr = gm0 + lr;
                        if (gr < M) {
                            as_out[(size_t)gr * H + hh] = ps + sAl[lr][0];
                            ad_out[(size_t)gr * H + hh] = pd + sAl[lr][1];
                        }
                    }
                }
            }
        }
    }
}

// ---------------- GAT agg L1 (H=4): 1 wave/node, fp8 gather, fused logits -----
__global__ __launch_bounds__(256) void gat_agg_l1(const unsigned* __restrict__ hq,   // fp8 rows, 128 dwords
                                                  const float4* __restrict__ as4,
                                                  const float4* __restrict__ ad4,
                                                  const int* __restrict__ rowptr,
                                                  const int* __restrict__ esrc,
                                                  const float* __restrict__ bias,
                                                  unsigned short* __restrict__ out, int N) {
    __shared__ float wlds_all[4][256];
    int w = threadIdx.x >> 6, lane = threadIdx.x & 63;
    int n = blockIdx.x * 4 + w;
    if (n >= N) return;
    float* wlds = wlds_all[w];
    int begin = rowptr[n], deg = rowptr[n + 1] - begin;
    float4 adn = ad4[n];

    // chunk-0 edge logits cached in registers (common case: deg <= 64)
    int s_l0 = 0;
    float4 e0 = {-3.4e38f, -3.4e38f, -3.4e38f, -3.4e38f};
    if (lane < deg) {
        s_l0 = esrc[begin + lane];
        float4 u = as4[s_l0];
        e0.x = LRELU(u.x + adn.x); e0.y = LRELU(u.y + adn.y);
        e0.z = LRELU(u.z + adn.z); e0.w = LRELU(u.w + adn.w);
    }
    // pass 1: per-head max
    float4 m = e0;
    for (int base = 64; base < deg; base += 64) {
        int j = base + lane;
        if (j < deg) {
            float4 u = as4[esrc[begin + j]];
            m.x = fmaxf(m.x, LRELU(u.x + adn.x)); m.y = fmaxf(m.y, LRELU(u.y + adn.y));
            m.z = fmaxf(m.z, LRELU(u.z + adn.z)); m.w = fmaxf(m.w, LRELU(u.w + adn.w));
        }
    }
#pragma unroll
    for (int o = 32; o >= 1; o >>= 1) {
        m.x = fmaxf(m.x, __shfl_xor(m.x, o));
        m.y = fmaxf(m.y, __shfl_xor(m.y, o));
        m.z = fmaxf(m.z, __shfl_xor(m.z, o));
        m.w = fmaxf(m.w, __shfl_xor(m.w, o));
    }
    // pass 2: per-head sum of exp
    float4 s4 = {0.f, 0.f, 0.f, 0.f};
    if (lane < deg) {
        s4.x = __expf(e0.x - m.x); s4.y = __expf(e0.y - m.y);
        s4.z = __expf(e0.z - m.z); s4.w = __expf(e0.w - m.w);
    }
    for (int base = 64; base < deg; base += 64) {
        int j = base + lane;
        if (j < deg) {
            float4 u = as4[esrc[begin + j]];
            s4.x += __expf(LRELU(u.x + adn.x) - m.x); s4.y += __expf(LRELU(u.y + adn.y) - m.y);
            s4.z += __expf(LRELU(u.z + adn.z) - m.z); s4.w += __expf(LRELU(u.w + adn.w) - m.w);
        }
    }
#pragma unroll
    for (int o = 32; o >= 1; o >>= 1) {
        s4.x += __shfl_xor(s4.x, o); s4.y += __shfl_xor(s4.y, o);
        s4.z += __shfl_xor(s4.z, o); s4.w += __shfl_xor(s4.w, o);
    }
    float4 inv = {1.f / (s4.x + 1e-16f), 1.f / (s4.y + 1e-16f),
                  1.f / (s4.z + 1e-16f), 1.f / (s4.w + 1e-16f)};

    // pass 3: weighted fp8 gather, 4-edge unroll
    float acc[8] = {};
    int h = lane >> 4;
#define ACC_E1(q, wgt) { \
    f32x2 p0 = __builtin_amdgcn_cvt_pk_f32_fp8((int)q.x, false); \
    f32x2 p1 = __builtin_amdgcn_cvt_pk_f32_fp8((int)q.x, true);  \
    f32x2 p2 = __builtin_amdgcn_cvt_pk_f32_fp8((int)q.y, false); \
    f32x2 p3 = __builtin_amdgcn_cvt_pk_f32_fp8((int)q.y, true);  \
    acc[0] += wgt * p0.x; acc[1] += wgt * p0.y; acc[2] += wgt * p1.x; acc[3] += wgt * p1.y; \
    acc[4] += wgt * p2.x; acc[5] += wgt * p2.y; acc[6] += wgt * p3.x; acc[7] += wgt * p3.y; }

    for (int base = 0; base < deg; base += 64) {
        int j = base + lane;
        int len = min(64, deg - base);
        int s_l = s_l0;
        float4 e = e0;
        if (base > 0 && j < deg) {
            s_l = esrc[begin + j];
            float4 u = as4[s_l];
            e.x = LRELU(u.x + adn.x); e.y = LRELU(u.y + adn.y);
            e.z = LRELU(u.z + adn.z); e.w = LRELU(u.w + adn.w);
        }
        if (j < deg) {
            float4 wv4 = {__expf(e.x - m.x) * inv.x, __expf(e.y - m.y) * inv.y,
                          __expf(e.z - m.z) * inv.z, __expf(e.w - m.w) * inv.w};
            *(float4*)&wlds[lane * 4] = wv4;   // wave-private region: no barrier
        }
        int c = 0;
        for (; c + 4 <= len; c += 4) {
            int s0 = __builtin_amdgcn_readlane(s_l, c);
            int s1 = __builtin_amdgcn_readlane(s_l, c + 1);
            int s2 = __builtin_amdgcn_readlane(s_l, c + 2);
            int s3 = __builtin_amdgcn_readlane(s_l, c + 3);
            uint2 q0 = *((const uint2*)(hq + (size_t)s0 * 128) + lane);
            uint2 q1 = *((const uint2*)(hq + (size_t)s1 * 128) + lane);
            uint2 q2 = *((const uint2*)(hq + (size_t)s2 * 128) + lane);
            uint2 q3 = *((const uint2*)(hq + (size_t)s3 * 128) + lane);
            float w0 = wlds[c * 4 + h];
            float w1 = wlds[c * 4 + 4 + h];
            float w2 = wlds[c * 4 + 8 + h];
            float w3 = wlds[c * 4 + 12 + h];
            ACC_E1(q0, w0); ACC_E1(q1, w1); ACC_E1(q2, w2); ACC_E1(q3, w3);
        }
        for (; c < len; c++) {
            int s0 = __builtin_amdgcn_readlane(s_l, c);
            uint2 q0 = *((const uint2*)(hq + (size_t)s0 * 128) + lane);
            float w0 = wlds[c * 4 + h];
            ACC_E1(q0, w0);
        }
    }
#undef ACC_E1
    // epilogue: bias + ELU + pack bf16x8 -> one 16B store
    int f0 = lane * 8;
    unsigned pk[4];
#pragma unroll
    for (int k = 0; k < 4; k++) {
        float v0 = acc[2 * k] + bias[f0 + 2 * k];
        float v1 = acc[2 * k + 1] + bias[f0 + 2 * k + 1];
        v0 = v0 > 0.f ? v0 : (__expf(v0) - 1.f);
        v1 = v1 > 0.f ? v1 : (__expf(v1) - 1.f);
        pk[k] = (unsigned)f2b(v0) | ((unsigned)f2b(v1) << 16);
    }
    uint4 pv = {pk[0], pk[1], pk[2], pk[3]};
    *((uint4*)(out + (size_t)n * 512) + lane) = pv;
}

// ---------------- GAT agg L2 (H=1): 1 wave/node, fp8 gather, fused logits -----
__global__ __launch_bounds__(256) void gat_agg_l2(const unsigned char* __restrict__ hq,  // fp8 rows, 128 B
                                                  const float* __restrict__ as,
                                                  const float* __restrict__ ad,
                                                  const int* __restrict__ rowptr,
                                                  const int* __restrict__ esrc,
                                                  const float* __restrict__ bias,
                                                  float* __restrict__ out, int N) {
    int w = threadIdx.x >> 6, lane = threadIdx.x & 63;
    int n = blockIdx.x * 4 + w;
    if (n >= N) return;
    int begin = rowptr[n], deg = rowptr[n + 1] - begin;
    float adn = ad[n];

    int s_l0 = 0;
    float e0 = -3.4e38f;
    if (lane < deg) {
        s_l0 = esrc[begin + lane];
        e0 = LRELU(as[s_l0] + adn);
    }
    float m = e0;
    for (int base = 64; base < deg; base += 64) {
        int j = base + lane;
        if (j < deg) m = fmaxf(m, LRELU(as[esrc[begin + j]] + adn));
    }
#pragma unroll
    for (int o = 32; o >= 1; o >>= 1) m = fmaxf(m, __shfl_xor(m, o));

    float s = (lane < deg) ? __expf(e0 - m) : 0.f;
    for (int base = 64; base < deg; base += 64) {
        int j = base + lane;
        if (j < deg) s += __expf(LRELU(as[esrc[begin + j]] + adn) - m);
    }
#pragma unroll
    for (int o = 32; o >= 1; o >>= 1) s += __shfl_xor(s, o);
    float inv = 1.f / (s + 1e-16f);

    float acc0 = 0.f, acc1 = 0.f;
    for (int base = 0; base < deg; base += 64) {
        int j = base + lane;
        int len = min(64, deg - base);
        int s_l = s_l0;
        float e = e0;
        if (base > 0 && j < deg) {
            s_l = esrc[begin + j];
            e = LRELU(as[s_l] + adn);
        }
        float w_l = (j < deg) ? __expf(e - m) * inv : 0.f;
        int c = 0;
        for (; c + 4 <= len; c += 4) {
            int sp0 = __builtin_amdgcn_readlane(s_l, c);
            int sp1 = __builtin_amdgcn_readlane(s_l, c + 1);
            int sp2 = __builtin_amdgcn_readlane(s_l, c + 2);
            int sp3 = __builtin_amdgcn_readlane(s_l, c + 3);
            unsigned short u0 = *((const unsigned short*)(hq + (size_t)sp0 * 128) + lane);
            unsigned short u1 = *((const unsigned short*)(hq + (size_t)sp1 * 128) + lane);
            unsigned short u2 = *((const unsigned short*)(hq + (size_t)sp2 * 128) + lane);
            unsigned short u3 = *((const unsigned short*)(hq + (size_t)sp3 * 128) + lane);
            float w0 = rl_f(w_l, c), w1 = rl_f(w_l, c + 1);
            float w2 = rl_f(w_l, c + 2), w3 = rl_f(w_l, c + 3);
            f32x2 p0 = __builtin_amdgcn_cvt_pk_f32_fp8((int)u0, false);
            f32x2 p1 = __builtin_amdgcn_cvt_pk_f32_fp8((int)u1, false);
            f32x2 p2 = __builtin_amdgcn_cvt_pk_f32_fp8((int)u2, false);
            f32x2 p3 = __builtin_amdgcn_cvt_pk_f32_fp8((int)u3, false);
            acc0 += w0 * p0.x; acc1 += w0 * p0.y;
            acc0 += w1 * p1.x; acc1 += w1 * p1.y;
            acc0 += w2 * p2.x; acc1 += w2 * p2.y;
            acc0 += w3 * p3.x; acc1 += w3 * p3.y;
        }
        for (; c < len; c++) {
            int sp0 = __builtin_amdgcn_readlane(s_l, c);
            float w0 = rl_f(w_l, c);
            unsigned short u0 = *((const unsigned short*)(hq + (size_t)sp0 * 128) + lane);
            f32x2 p0 = __builtin_amdgcn_cvt_pk_f32_fp8((int)u0, false);
            acc0 += w0 * p0.x; acc1 += w0 * p0.y;
        }
    }
    float v0 = acc0 + bias[lane * 2];
    float v1 = acc1 + bias[lane * 2 + 1];
    v0 = v0 > 0.f ? v0 : (__expf(v0) - 1.f);
    v1 = v1 > 0.f ? v1 : (__expf(v1) - 1.f);
    float2 pv = {v0, v1};
    *(float2*)&out[(size_t)n * 128 + lane * 2] = pv;
}

// ---------------- mean pool + final GEMV (fused via done-counter) -------------
__global__ __launch_bounds__(256) void pool_final_kernel(const float* __restrict__ o2,
                                                         float* __restrict__ pool,
                                                         int* __restrict__ done,
                                                         const float* __restrict__ Wout,
                                                         const float* __restrict__ bout,
                                                         float* __restrict__ out,
                                                         int N, int nblocks, float invN) {
    __shared__ float4 sred[256];
    int f4 = threadIdx.x & 31;
    int r = blockIdx.x * 256 + (threadIdx.x >> 5);
    float4 acc = {0.f, 0.f, 0.f, 0.f};
    for (int i = 0; i < 32; i++, r += 8) {
        if (r < N) {
            float4 v = *(const float4*)&o2[(size_t)r * 128 + f4 * 4];
            acc.x += v.x; acc.y += v.y; acc.z += v.z; acc.w += v.w;
        }
    }
    sred[threadIdx.x] = acc;
    __syncthreads();
    if (threadIdx.x < 32) {
        float4 t = sred[threadIdx.x];
#pragma unroll
        for (int k = 1; k < 8; k++) {
            float4 u = sred[threadIdx.x + 32 * k];
            t.x += u.x; t.y += u.y; t.z += u.z; t.w += u.w;
        }
        atomicAdd(&pool[f4 * 4 + 0], t.x);
        atomicAdd(&pool[f4 * 4 + 1], t.y);
        atomicAdd(&pool[f4 * 4 + 2], t.z);
        atomicAdd(&pool[f4 * 4 + 3], t.w);
    }
    __threadfence();
    __shared__ int isLast;
    if (threadIdx.x == 0) isLast = (atomicAdd(done, 1) == nblocks - 1);
    __syncthreads();
    if (isLast) {
        __shared__ float spool[128];
        if (threadIdx.x < 128) spool[threadIdx.x] = atomicAdd(&pool[threadIdx.x], 0.f);
        __syncthreads();
        int o = threadIdx.x;
        float a = 0.f;
        for (int k = 0; k < 128; k++) a += spool[k] * Wout[k * 256 + o];
        out[o] = a * invN + bout[o];
    }
}

// ---------------- launch ------------------------------------------------------
extern "C" void kernel_launch(void* const* d_in, const int* in_sizes, int n_in,
                              void* d_out, int out_size, void* d_ws, size_t ws_size,
                              hipStream_t stream) {
    const float* x      = (const float*)d_in[0];
    const int*   ei     = (const int*)d_in[1];
    const float* W_emb  = (const float*)d_in[2];
    const float* b_emb  = (const float*)d_in[3];
    const float* W1     = (const float*)d_in[4];
    const float* a1_src = (const float*)d_in[5];
    const float* a1_dst = (const float*)d_in[6];
    const float* b1     = (const float*)d_in[7];
    const float* W2     = (const float*)d_in[8];
    const float* a2_src = (const float*)d_in[9];
    const float* a2_dst = (const float*)d_in[10];
    const float* b2     = (const float*)d_in[11];
    const float* W_out  = (const float*)d_in[12];
    const float* b_out  = (const float*)d_in[13];
    float* out = (float*)d_out;

    const int N = in_sizes[0] / 64;   // 25000
    const int E = in_sizes[1] / 2;    // 400000
    const int Etot = E + N;
    const int nb = (N + 255) / 256;

    char* ws = (char*)d_ws;
    size_t off = 0;
    auto alloc = [&](size_t bytes) -> void* {
        void* p = ws + off;
        off = (off + bytes + 255) & ~(size_t)255;
        return p;
    };
    typedef unsigned short u16;
    u16* xb    = (u16*)alloc((size_t)N * 64 * 2);
    u16* WeT   = (u16*)alloc((size_t)128 * 64 * 2);
    u16* W1T   = (u16*)alloc((size_t)512 * 128 * 2);
    u16* W2T   = (u16*)alloc((size_t)128 * 512 * 2);
    u16* h0b   = (u16*)alloc((size_t)N * 128 * 2);
    unsigned char* h1q = (unsigned char*)alloc((size_t)N * 512);   // fp8
    u16* o1b   = (u16*)alloc((size_t)N * 512 * 2);
    unsigned char* h2q = (unsigned char*)alloc((size_t)N * 128);   // fp8
    float* o2  = (float*)alloc((size_t)N * 128 * 4);
    float* as1 = (float*)alloc((size_t)N * 4 * 4);
    float* ad1 = (float*)alloc((size_t)N * 4 * 4);
    float* as2 = (float*)alloc((size_t)N * 4);
    float* ad2 = (float*)alloc((size_t)N * 4);
    float* pool = (float*)alloc(128 * 4);
    int* done   = (int*)alloc(256);
    int* rowptr = (int*)alloc((size_t)(N + 1) * 4);
    int* deg    = (int*)alloc((size_t)N * 4);
    int* cursor = (int*)alloc((size_t)N * 4);
    int* bsum   = (int*)alloc(128 * 4);
    int* boff   = (int*)alloc(128 * 4);
    int* esrc   = (int*)alloc((size_t)Etot * 4);

    // zero scratch + CSR build
    zero_kernel<<<(2 * N + 129 + 255) / 256, 256, 0, stream>>>(deg, cursor, pool, done, N);
    int blocksE = (Etot + 255) / 256;
    deg_count_kernel<<<blocksE, 256, 0, stream>>>(ei, E, N, deg);
    scan_pass1<<<nb, 256, 0, stream>>>(deg, rowptr, bsum, N);
    scan_pass2<<<1, 128, 0, stream>>>(bsum, boff, rowptr, nb, N);
    scan_pass3<<<nb, 256, 0, stream>>>(rowptr, boff, N);
    scatter_kernel<<<blocksE, 256, 0, stream>>>(ei, E, N, rowptr, cursor, esrc);

    // bf16 conversions + weight transposes
    int Nx = N * 64;
    int prep_elems = Nx + 64 * 128 + 128 * 512 + 512 * 128;
    prep_kernel<<<(prep_elems + 255) / 256, 256, 0, stream>>>(x, W_emb, W1, W2, xb, WeT, W1T, W2T, Nx);

    int mtiles = (N + 127) / 128;
    // h0 = relu(x @ W_emb + b_emb)  [N,128] bf16
    gemm_mfma_nt<1, 0, 0, 1><<<dim3(1, mtiles), 256, 0, stream>>>(
        xb, WeT, b_emb, h0b, nullptr, nullptr, nullptr, nullptr, N, 128, 64);
    // h1pre = h0 @ W1  [N,512] fp8 + fused alpha1 (f32-exact)
    gemm_mfma_nt<0, 1, 1, 4><<<dim3(4, mtiles), 256, 0, stream>>>(
        h0b, W1T, nullptr, h1q, a1_src, a1_dst, as1, ad1, N, 512, 128);

    // layer-1 aggregation (logits on the fly, fp8 gather)
    gat_agg_l1<<<(N + 3) / 4, 256, 0, stream>>>((const unsigned*)h1q, (const float4*)as1,
                                                (const float4*)ad1, rowptr, esrc, b1, o1b, N);

    // h2pre = o1 @ W2  [N,128] fp8 + fused alpha2
    gemm_mfma_nt<0, 1, 1, 1><<<dim3(1, mtiles), 256, 0, stream>>>(
        o1b, W2T, nullptr, h2q, a2_src, a2_dst, as2, ad2, N, 128, 512);

    // layer-2 aggregation
    gat_agg_l2<<<(N + 3) / 4, 256, 0, stream>>>(h2q, as2, ad2, rowptr, esrc, b2, o2, N);

    // mean pool + final GEMV
    int npb = (N + 255) / 256;
    pool_final_kernel<<<npb, 256, 0, stream>>>(o2, pool, done, W_out, b_out, out,
                                               N, npb, 1.f / (float)N);
}

// Round 8
// 277.269 us; speedup vs baseline: 1.8267x; 1.0116x over previous
//
#include <hip/hip_runtime.h>
#include <hip/hip_bf16.h>

// N=25000, E=400000 (+N self loops), F_IN=64, HID=128, HEADS=4, OUT=256
// bf16 MFMA GEMMs (embed GEMM fused into layer-1 GEMM via LDS round-trip);
// node-feature gather operands stored fp8(e4m3); alpha dots fused into GEMM
// epilogues (f32-exact); edge logits computed on the fly in agg kernels.
// NOTE: cooperative grid.sync measured ~30us/barrier on gfx950 — never use it
// to fuse cheap kernels (round-5 regression). Pool fusion into agg_l2 rejected:
// 6250 blocks x 128 atomicAdds to 128 addrs = contended; 98-block pool is fine.

#define LRELU(x) ((x) > 0.f ? (x) : 0.2f * (x))

typedef short bf16x8 __attribute__((ext_vector_type(8)));
typedef float f32x4 __attribute__((ext_vector_type(4)));
typedef float f32x2 __attribute__((ext_vector_type(2)));

static __device__ __forceinline__ unsigned short f2b(float f) {
    union { float f; unsigned u; } x; x.f = f;
    unsigned r = x.u + 0x7fff + ((x.u >> 16) & 1);
    return (unsigned short)(r >> 16);
}
static __device__ __forceinline__ float rl_f(float v, int c) {
    return __int_as_float(__builtin_amdgcn_readlane(__float_as_int(v), c));
}
static __device__ __forceinline__ unsigned char f2fp8(float v) {
    int p = __builtin_amdgcn_cvt_pk_fp8_f32(v, v, 0, false);
    return (unsigned char)(p & 0xff);
}

// ---------------- zero scratch ------------------------------------------------
__global__ void zero_kernel(int* __restrict__ deg, int* __restrict__ cursor,
                            float* __restrict__ pool, int* __restrict__ done, int N) {
    int i = blockIdx.x * blockDim.x + threadIdx.x;
    if (i < N) deg[i] = 0;
    else if (i < 2 * N) cursor[i - N] = 0;
    else if (i < 2 * N + 128) pool[i - 2 * N] = 0.f;
    else if (i == 2 * N + 128) *done = 0;
}

// ---------------- CSR build (6 small kernels — proven fast) -------------------
__global__ void deg_count_kernel(const int* __restrict__ ei, int E, int N, int* __restrict__ deg) {
    int i = blockIdx.x * blockDim.x + threadIdx.x;
    if (i < E) atomicAdd(&deg[ei[E + i]], 1);
    else if (i < E + N) atomicAdd(&deg[i - E], 1);
}

__global__ __launch_bounds__(256) void scan_pass1(const int* __restrict__ deg, int* __restrict__ rowptr,
                                                  int* __restrict__ bsum, int N) {
    __shared__ int sd[256];
    int t = threadIdx.x, i = blockIdx.x * 256 + t;
    int d = (i < N) ? deg[i] : 0;
    sd[t] = d;
    __syncthreads();
    for (int off = 1; off < 256; off <<= 1) {
        int v = (t >= off) ? sd[t - off] : 0;
        __syncthreads();
        sd[t] += v;
        __syncthreads();
    }
    if (i < N) rowptr[i] = sd[t] - d;
    if (t == 255) bsum[blockIdx.x] = sd[t];
}

__global__ __launch_bounds__(128) void scan_pass2(const int* __restrict__ bsum, int* __restrict__ boff,
                                                  int* __restrict__ rowptr, int nb, int N) {
    __shared__ int sd[128];
    int t = threadIdx.x;
    int d = (t < nb) ? bsum[t] : 0;
    sd[t] = d;
    __syncthreads();
    for (int off = 1; off < 128; off <<= 1) {
        int v = (t >= off) ? sd[t - off] : 0;
        __syncthreads();
        sd[t] += v;
        __syncthreads();
    }
    if (t < nb) boff[t] = sd[t] - d;
    if (t == 127) rowptr[N] = sd[t];
}

__global__ __launch_bounds__(256) void scan_pass3(int* __restrict__ rowptr, const int* __restrict__ boff, int N) {
    int i = blockIdx.x * 256 + threadIdx.x;
    if (i < N) rowptr[i] += boff[blockIdx.x];
}

__global__ void scatter_kernel(const int* __restrict__ ei, int E, int N,
                               const int* __restrict__ rowptr, int* __restrict__ cursor,
                               int* __restrict__ esrc) {
    int i = blockIdx.x * blockDim.x + threadIdx.x;
    int s, d;
    if (i < E) { s = ei[i]; d = ei[E + i]; }
    else if (i < E + N) { s = i - E; d = s; }
    else return;
    int pos = rowptr[d] + atomicAdd(&cursor[d], 1);
    esrc[pos] = s;
}

// ---------------- prep: x->bf16 + 3 weight transposes (one dispatch) ----------
__global__ void prep_kernel(const float* __restrict__ x, const float* __restrict__ We,
                            const float* __restrict__ W1, const float* __restrict__ W2,
                            unsigned short* __restrict__ xb, unsigned short* __restrict__ WeT,
                            unsigned short* __restrict__ W1T, unsigned short* __restrict__ W2T,
                            int Nx) {
    int i = blockIdx.x * blockDim.x + threadIdx.x;
    if (i < Nx) { xb[i] = f2b(x[i]); return; }
    i -= Nx;
    if (i < 64 * 128) { int k = i >> 7, n = i & 127; WeT[n * 64 + k] = f2b(We[i]); return; }
    i -= 64 * 128;
    if (i < 128 * 512) { int k = i >> 9, n = i & 511; W1T[n * 128 + k] = f2b(W1[i]); return; }
    i -= 128 * 512;
    if (i < 512 * 128) { int k = i >> 7, n = i & 127; W2T[n * 512 + k] = f2b(W2[i]); return; }
}

// ---------------- fused GEMM1+2: h1 = relu(x@We+be)@W1, fp8 out + alpha -------
// grid (4, mtiles): blockIdx.x = head (128-col tile of W1T), blockIdx.y = rows.
__global__ __launch_bounds__(256) void gemm12_fused(const unsigned short* __restrict__ A,    // xb [M,64]
                                                    const unsigned short* __restrict__ WeT,  // [128,64]
                                                    const float* __restrict__ b_emb,         // [128]
                                                    const unsigned short* __restrict__ W1T,  // [512,128]
                                                    unsigned char* __restrict__ C8,          // [M,512] fp8
                                                    const float* __restrict__ a_src,
                                                    const float* __restrict__ a_dst,
                                                    float* __restrict__ as_out,
                                                    float* __restrict__ ad_out, int M) {
    // LDS union: phase1 [Asx 128x72 | Bwe 128x72] ; phase2 [h0s 128x132 | Bs 128x40]
    __shared__ __align__(16) unsigned short smem[22016];
    unsigned short* Asx = smem;            // 9216 shorts
    unsigned short* Bwe = smem + 9216;     // 9216 shorts
    unsigned short* h0s = smem;            // 16896 shorts
    unsigned short* Bs  = smem + 16896;    // 5120 shorts
    __shared__ float sAl[128][2];

    int tid = threadIdx.x;
    int gm0 = blockIdx.y * 128, gn0 = blockIdx.x * 128;
    int w = tid >> 6, lane = tid & 63;
    int wrow = (w >> 1) * 64, wcol = (w & 1) * 64;
    int l15 = lane & 15, quad = lane >> 4;

    // ---- phase 1: h0 tile = relu(x@We + be) ----
    f32x4 acc[4][4];
#pragma unroll
    for (int i = 0; i < 4; i++)
#pragma unroll
        for (int j = 0; j < 4; j++) acc[i][j] = {0.f, 0.f, 0.f, 0.f};

#pragma unroll
    for (int rr = 0; rr < 4; rr++) {
        int lin = tid + rr * 256;
        int row = lin >> 3;
        int cg = (lin & 7) * 8;
        int grow = gm0 + row; if (grow >= M) grow = M - 1;
        *(uint4*)&Asx[row * 72 + cg] = *(const uint4*)&A[(size_t)grow * 64 + cg];
        *(uint4*)&Bwe[row * 72 + cg] = *(const uint4*)&WeT[(size_t)row * 64 + cg];
    }
    __syncthreads();
#pragma unroll
    for (int k0 = 0; k0 < 64; k0 += 32) {
        bf16x8 af[4], bfr[4];
#pragma unroll
        for (int i = 0; i < 4; i++) {
            af[i]  = *(const bf16x8*)&Asx[(wrow + i * 16 + l15) * 72 + k0 + quad * 8];
            bfr[i] = *(const bf16x8*)&Bwe[(wcol + i * 16 + l15) * 72 + k0 + quad * 8];
        }
#pragma unroll
        for (int i = 0; i < 4; i++)
#pragma unroll
            for (int j = 0; j < 4; j++)
                acc[i][j] = __builtin_amdgcn_mfma_f32_16x16x32_bf16(af[i], bfr[j], acc[i][j], 0, 0, 0);
    }
    __syncthreads();   // all waves done reading Asx/Bwe before h0s overwrites them

    // bias + relu + bf16, deposit into h0s[row][col]
#pragma unroll
    for (int j = 0; j < 4; j++) {
        int col = wcol + j * 16 + l15;
        float bv = b_emb[col];
#pragma unroll
        for (int i = 0; i < 4; i++) {
            int row = wrow + i * 16 + quad * 4;
#pragma unroll
            for (int r = 0; r < 4; r++) {
                float v = fmaxf(acc[i][j][r] + bv, 0.f);
                h0s[(row + r) * 132 + col] = f2b(v);
            }
        }
    }

    // ---- phase 2: h1 tile = h0 @ W1 (K=128), cols gn0..gn0+127 ----
#pragma unroll
    for (int i = 0; i < 4; i++)
#pragma unroll
        for (int j = 0; j < 4; j++) acc[i][j] = {0.f, 0.f, 0.f, 0.f};

    for (int k0 = 0; k0 < 128; k0 += 32) {
#pragma unroll
        for (int rr = 0; rr < 2; rr++) {
            int lin = tid + rr * 256;
            int row = lin >> 2;
            int cg = (lin & 3) * 8;
            *(uint4*)&Bs[row * 40 + cg] = *(const uint4*)&W1T[(size_t)(gn0 + row) * 128 + k0 + cg];
        }
        __syncthreads();
        bf16x8 af[4], bfr[4];
#pragma unroll
        for (int i = 0; i < 4; i++) {
            af[i]  = *(const bf16x8*)&h0s[(wrow + i * 16 + l15) * 132 + k0 + quad * 8];
            bfr[i] = *(const bf16x8*)&Bs[(wcol + i * 16 + l15) * 40 + quad * 8];
        }
#pragma unroll
        for (int i = 0; i < 4; i++)
#pragma unroll
            for (int j = 0; j < 4; j++)
                acc[i][j] = __builtin_amdgcn_mfma_f32_16x16x32_bf16(af[i], bfr[j], acc[i][j], 0, 0, 0);
        __syncthreads();
    }

    // fp8 store
#pragma unroll
    for (int i = 0; i < 4; i++) {
        int row = gm0 + wrow + i * 16 + quad * 4;
#pragma unroll
        for (int j = 0; j < 4; j++) {
            int col = gn0 + wcol + j * 16 + l15;
#pragma unroll
            for (int r = 0; r < 4; r++) {
                int gr = row + r;
                if (gr < M) C8[(size_t)gr * 512 + col] = f2fp8(acc[i][j][r]);
            }
        }
    }

    // fused alpha (head hh = blockIdx.x), f32-exact from accumulators
    {
        int hh = blockIdx.x;
        float as_c[4], ad_c[4];
#pragma unroll
        for (int j = 0; j < 4; j++) {
            int c = gn0 + wcol + j * 16 + l15;
            as_c[j] = a_src[c];
            ad_c[j] = a_dst[c];
        }
#pragma unroll
        for (int i = 0; i < 4; i++) {
#pragma unroll
            for (int r = 0; r < 4; r++) {
                float ps = 0.f, pd = 0.f;
#pragma unroll
                for (int j = 0; j < 4; j++) {
                    ps += acc[i][j][r] * as_c[j];
                    pd += acc[i][j][r] * ad_c[j];
                }
#pragma unroll
                for (int o = 1; o < 16; o <<= 1) {
                    ps += __shfl_xor(ps, o);
                    pd += __shfl_xor(pd, o);
                }
                if (wcol == 64 && l15 == 0) {
                    int lr = wrow + i * 16 + quad * 4 + r;
                    sAl[lr][0] = ps;
                    sAl[lr][1] = pd;
                }
            }
        }
        __syncthreads();
        if (wcol == 0) {
#pragma unroll
            for (int i = 0; i < 4; i++) {
#pragma unroll
                for (int r = 0; r < 4; r++) {
                    float ps = 0.f, pd = 0.f;
#pragma unroll
                    for (int j = 0; j < 4; j++) {
                        ps += acc[i][j][r] * as_c[j];
                        pd += acc[i][j][r] * ad_c[j];
                    }
#pragma unroll
                    for (int o = 1; o < 16; o <<= 1) {
                        ps += __shfl_xor(ps, o);
                        pd += __shfl_xor(pd, o);
                    }
                    if (l15 == 0) {
                        int lr = wrow + i * 16 + quad * 4 + r;
                        int gr = gm0 + lr;
                        if (gr < M) {
                            as_out[(size_t)gr * 4 + hh] = ps + sAl[lr][0];
                            ad_out[(size_t)gr * 4 + hh] = pd + sAl[lr][1];
                        }
                    }
                }
            }
        }
    }
}

// ---------------- MFMA bf16 NT GEMM (layer 2): fp8 out + fused alpha ----------
template <int ACT, int OFMT, int ALPHA, int H>
__global__ __launch_bounds__(256) void gemm_mfma_nt(const unsigned short* __restrict__ A,
                                                    const unsigned short* __restrict__ Bt,
                                                    const float* __restrict__ bias,
                                                    void* __restrict__ Cout,
                                                    const float* __restrict__ a_src,
                                                    const float* __restrict__ a_dst,
                                                    float* __restrict__ as_out,
                                                    float* __restrict__ ad_out,
                                                    int M, int N, int K) {
    __shared__ __align__(16) unsigned short As[128 * 40];
    __shared__ __align__(16) unsigned short Bs[128 * 40];
    __shared__ float sAl[128][2];
    int tid = threadIdx.x;
    int gm0 = blockIdx.y * 128, gn0 = blockIdx.x * 128;
    int w = tid >> 6, lane = tid & 63;
    int wrow = (w >> 1) * 64, wcol = (w & 1) * 64;
    int l15 = lane & 15, quad = lane >> 4;

    f32x4 acc[4][4];
#pragma unroll
    for (int i = 0; i < 4; i++)
#pragma unroll
        for (int j = 0; j < 4; j++) acc[i][j] = {0.f, 0.f, 0.f, 0.f};

    for (int k0 = 0; k0 < K; k0 += 32) {
#pragma unroll
        for (int rr = 0; rr < 2; rr++) {
            int lin = tid + rr * 256;
            int row = lin >> 2;
            int cg = (lin & 3) * 8;
            int grow = gm0 + row; if (grow >= M) grow = M - 1;
            uint4 va = *(const uint4*)&A[(size_t)grow * K + k0 + cg];
            *(uint4*)&As[row * 40 + cg] = va;
            uint4 vb = *(const uint4*)&Bt[(size_t)(gn0 + row) * K + k0 + cg];
            *(uint4*)&Bs[row * 40 + cg] = vb;
        }
        __syncthreads();
        bf16x8 af[4], bfr[4];
#pragma unroll
        for (int i = 0; i < 4; i++) {
            af[i]  = *(const bf16x8*)&As[(wrow + i * 16 + l15) * 40 + quad * 8];
            bfr[i] = *(const bf16x8*)&Bs[(wcol + i * 16 + l15) * 40 + quad * 8];
        }
#pragma unroll
        for (int i = 0; i < 4; i++)
#pragma unroll
            for (int j = 0; j < 4; j++)
                acc[i][j] = __builtin_amdgcn_mfma_f32_16x16x32_bf16(af[i], bfr[j], acc[i][j], 0, 0, 0);
        __syncthreads();
    }

    if (OFMT == 0) {
        unsigned short* C = (unsigned short*)Cout;
#pragma unroll
        for (int i = 0; i < 4; i++) {
            int row = gm0 + wrow + i * 16 + quad * 4;
#pragma unroll
            for (int j = 0; j < 4; j++) {
                int col = gn0 + wcol + j * 16 + l15;
                float bv = bias ? bias[col] : 0.f;
#pragma unroll
                for (int r = 0; r < 4; r++) {
                    int gr = row + r;
                    if (gr < M) {
                        float v = acc[i][j][r] + bv;
                        if (ACT == 1) v = fmaxf(v, 0.f);
                        C[(size_t)gr * N + col] = f2b(v);
                    }
                }
            }
        }
    } else {
        unsigned char* C8 = (unsigned char*)Cout;
#pragma unroll
        for (int i = 0; i < 4; i++) {
            int row = gm0 + wrow + i * 16 + quad * 4;
#pragma unroll
            for (int j = 0; j < 4; j++) {
                int col = gn0 + wcol + j * 16 + l15;
#pragma unroll
                for (int r = 0; r < 4; r++) {
                    int gr = row + r;
                    if (gr < M) C8[(size_t)gr * N + col] = f2fp8(acc[i][j][r]);
                }
            }
        }
    }

    if (ALPHA) {
        int hh = blockIdx.x;
        float as_c[4], ad_c[4];
#pragma unroll
        for (int j = 0; j < 4; j++) {
            int c = gn0 + wcol + j * 16 + l15;
            as_c[j] = a_src[c];
            ad_c[j] = a_dst[c];
        }
#pragma unroll
        for (int i = 0; i < 4; i++) {
#pragma unroll
            for (int r = 0; r < 4; r++) {
                float ps = 0.f, pd = 0.f;
#pragma unroll
                for (int j = 0; j < 4; j++) {
                    ps += acc[i][j][r] * as_c[j];
                    pd += acc[i][j][r] * ad_c[j];
                }
#pragma unroll
                for (int o = 1; o < 16; o <<= 1) {
                    ps += __shfl_xor(ps, o);
                    pd += __shfl_xor(pd, o);
                }
                if (wcol == 64 && l15 == 0) {
                    int lr = wrow + i * 16 + quad * 4 + r;
                    sAl[lr][0] = ps;
                    sAl[lr][1] = pd;
                }
            }
        }
        __syncthreads();
        if (wcol == 0) {
#pragma unroll
            for (int i = 0; i < 4; i++) {
#pragma unroll
                for (int r = 0; r < 4; r++) {
                    float ps = 0.f, pd = 0.f;
#pragma unroll
                    for (int j = 0; j < 4; j++) {
                        ps += acc[i][j][r] * as_c[j];
                        pd += acc[i][j][r] * ad_c[j];
                    }
#pragma unroll
                    for (int o = 1; o < 16; o <<= 1) {
                        ps += __shfl_xor(ps, o);
                        pd += __shfl_xor(pd, o);
                    }
                    if (l15 == 0) {
                        int lr = wrow + i * 16 + quad * 4 + r;
                        int gr = gm0 + lr;
                        if (gr < M) {
                            as_out[(size_t)gr * H + hh] = ps + sAl[lr][0];
                            ad_out[(size_t)gr * H + hh] = pd + sAl[lr][1];
                        }
                    }
                }
            }
        }
    }
}

// ---------------- GAT agg L1 (H=4): 1 wave/node, fp8 gather, fused logits -----
__global__ __launch_bounds__(256) void gat_agg_l1(const unsigned* __restrict__ hq,   // fp8 rows, 128 dwords
                                                  const float4* __restrict__ as4,
                                                  const float4* __restrict__ ad4,
                                                  const int* __restrict__ rowptr,
                                                  const int* __restrict__ esrc,
                                                  const float* __restrict__ bias,
                                                  unsigned short* __restrict__ out, int N) {
    __shared__ float wlds_all[4][256];
    int w = threadIdx.x >> 6, lane = threadIdx.x & 63;
    int n = blockIdx.x * 4 + w;
    if (n >= N) return;
    float* wlds = wlds_all[w];
    int begin = rowptr[n], deg = rowptr[n + 1] - begin;
    float4 adn = ad4[n];

    int s_l0 = 0;
    float4 e0 = {-3.4e38f, -3.4e38f, -3.4e38f, -3.4e38f};
    if (lane < deg) {
        s_l0 = esrc[begin + lane];
        float4 u = as4[s_l0];
        e0.x = LRELU(u.x + adn.x); e0.y = LRELU(u.y + adn.y);
        e0.z = LRELU(u.z + adn.z); e0.w = LRELU(u.w + adn.w);
    }
    float4 m = e0;
    for (int base = 64; base < deg; base += 64) {
        int j = base + lane;
        if (j < deg) {
            float4 u = as4[esrc[begin + j]];
            m.x = fmaxf(m.x, LRELU(u.x + adn.x)); m.y = fmaxf(m.y, LRELU(u.y + adn.y));
            m.z = fmaxf(m.z, LRELU(u.z + adn.z)); m.w = fmaxf(m.w, LRELU(u.w + adn.w));
        }
    }
#pragma unroll
    for (int o = 32; o >= 1; o >>= 1) {
        m.x = fmaxf(m.x, __shfl_xor(m.x, o));
        m.y = fmaxf(m.y, __shfl_xor(m.y, o));
        m.z = fmaxf(m.z, __shfl_xor(m.z, o));
        m.w = fmaxf(m.w, __shfl_xor(m.w, o));
    }
    float4 s4 = {0.f, 0.f, 0.f, 0.f};
    if (lane < deg) {
        s4.x = __expf(e0.x - m.x); s4.y = __expf(e0.y - m.y);
        s4.z = __expf(e0.z - m.z); s4.w = __expf(e0.w - m.w);
    }
    for (int base = 64; base < deg; base += 64) {
        int j = base + lane;
        if (j < deg) {
            float4 u = as4[esrc[begin + j]];
            s4.x += __expf(LRELU(u.x + adn.x) - m.x); s4.y += __expf(LRELU(u.y + adn.y) - m.y);
            s4.z += __expf(LRELU(u.z + adn.z) - m.z); s4.w += __expf(LRELU(u.w + adn.w) - m.w);
        }
    }
#pragma unroll
    for (int o = 32; o >= 1; o >>= 1) {
        s4.x += __shfl_xor(s4.x, o); s4.y += __shfl_xor(s4.y, o);
        s4.z += __shfl_xor(s4.z, o); s4.w += __shfl_xor(s4.w, o);
    }
    float4 inv = {1.f / (s4.x + 1e-16f), 1.f / (s4.y + 1e-16f),
                  1.f / (s4.z + 1e-16f), 1.f / (s4.w + 1e-16f)};

    float acc[8] = {};
    int h = lane >> 4;
#define ACC_E1(q, wgt) { \
    f32x2 p0 = __builtin_amdgcn_cvt_pk_f32_fp8((int)q.x, false); \
    f32x2 p1 = __builtin_amdgcn_cvt_pk_f32_fp8((int)q.x, true);  \
    f32x2 p2 = __builtin_amdgcn_cvt_pk_f32_fp8((int)q.y, false); \
    f32x2 p3 = __builtin_amdgcn_cvt_pk_f32_fp8((int)q.y, true);  \
    acc[0] += wgt * p0.x; acc[1] += wgt * p0.y; acc[2] += wgt * p1.x; acc[3] += wgt * p1.y; \
    acc[4] += wgt * p2.x; acc[5] += wgt * p2.y; acc[6] += wgt * p3.x; acc[7] += wgt * p3.y; }

    for (int base = 0; base < deg; base += 64) {
        int j = base + lane;
        int len = min(64, deg - base);
        int s_l = s_l0;
        float4 e = e0;
        if (base > 0 && j < deg) {
            s_l = esrc[begin + j];
            float4 u = as4[s_l];
            e.x = LRELU(u.x + adn.x); e.y = LRELU(u.y + adn.y);
            e.z = LRELU(u.z + adn.z); e.w = LRELU(u.w + adn.w);
        }
        if (j < deg) {
            float4 wv4 = {__expf(e.x - m.x) * inv.x, __expf(e.y - m.y) * inv.y,
                          __expf(e.z - m.z) * inv.z, __expf(e.w - m.w) * inv.w};
            *(float4*)&wlds[lane * 4] = wv4;
        }
        int c = 0;
        for (; c + 4 <= len; c += 4) {
            int s0 = __builtin_amdgcn_readlane(s_l, c);
            int s1 = __builtin_amdgcn_readlane(s_l, c + 1);
            int s2 = __builtin_amdgcn_readlane(s_l, c + 2);
            int s3 = __builtin_amdgcn_readlane(s_l, c + 3);
            uint2 q0 = *((const uint2*)(hq + (size_t)s0 * 128) + lane);
            uint2 q1 = *((const uint2*)(hq + (size_t)s1 * 128) + lane);
            uint2 q2 = *((const uint2*)(hq + (size_t)s2 * 128) + lane);
            uint2 q3 = *((const uint2*)(hq + (size_t)s3 * 128) + lane);
            float w0 = wlds[c * 4 + h];
            float w1 = wlds[c * 4 + 4 + h];
            float w2 = wlds[c * 4 + 8 + h];
            float w3 = wlds[c * 4 + 12 + h];
            ACC_E1(q0, w0); ACC_E1(q1, w1); ACC_E1(q2, w2); ACC_E1(q3, w3);
        }
        for (; c < len; c++) {
            int s0 = __builtin_amdgcn_readlane(s_l, c);
            uint2 q0 = *((const uint2*)(hq + (size_t)s0 * 128) + lane);
            float w0 = wlds[c * 4 + h];
            ACC_E1(q0, w0);
        }
    }
#undef ACC_E1
    int f0 = lane * 8;
    unsigned pk[4];
#pragma unroll
    for (int k = 0; k < 4; k++) {
        float v0 = acc[2 * k] + bias[f0 + 2 * k];
        float v1 = acc[2 * k + 1] + bias[f0 + 2 * k + 1];
        v0 = v0 > 0.f ? v0 : (__expf(v0) - 1.f);
        v1 = v1 > 0.f ? v1 : (__expf(v1) - 1.f);
        pk[k] = (unsigned)f2b(v0) | ((unsigned)f2b(v1) << 16);
    }
    uint4 pv = {pk[0], pk[1], pk[2], pk[3]};
    *((uint4*)(out + (size_t)n * 512) + lane) = pv;
}

// ---------------- GAT agg L2 (H=1): 1 wave/node, fp8 gather, fused logits -----
__global__ __launch_bounds__(256) void gat_agg_l2(const unsigned char* __restrict__ hq,
                                                  const float* __restrict__ as,
                                                  const float* __restrict__ ad,
                                                  const int* __restrict__ rowptr,
                                                  const int* __restrict__ esrc,
                                                  const float* __restrict__ bias,
                                                  float* __restrict__ out, int N) {
    int w = threadIdx.x >> 6, lane = threadIdx.x & 63;
    int n = blockIdx.x * 4 + w;
    if (n >= N) return;
    int begin = rowptr[n], deg = rowptr[n + 1] - begin;
    float adn = ad[n];

    int s_l0 = 0;
    float e0 = -3.4e38f;
    if (lane < deg) {
        s_l0 = esrc[begin + lane];
        e0 = LRELU(as[s_l0] + adn);
    }
    float m = e0;
    for (int base = 64; base < deg; base += 64) {
        int j = base + lane;
        if (j < deg) m = fmaxf(m, LRELU(as[esrc[begin + j]] + adn));
    }
#pragma unroll
    for (int o = 32; o >= 1; o >>= 1) m = fmaxf(m, __shfl_xor(m, o));

    float s = (lane < deg) ? __expf(e0 - m) : 0.f;
    for (int base = 64; base < deg; base += 64) {
        int j = base + lane;
        if (j < deg) s += __expf(LRELU(as[esrc[begin + j]] + adn) - m);
    }
#pragma unroll
    for (int o = 32; o >= 1; o >>= 1) s += __shfl_xor(s, o);
    float inv = 1.f / (s + 1e-16f);

    float acc0 = 0.f, acc1 = 0.f;
    for (int base = 0; base < deg; base += 64) {
        int j = base + lane;
        int len = min(64, deg - base);
        int s_l = s_l0;
        float e = e0;
        if (base > 0 && j < deg) {
            s_l = esrc[begin + j];
            e = LRELU(as[s_l] + adn);
        }
        float w_l = (j < deg) ? __expf(e - m) * inv : 0.f;
        int c = 0;
        for (; c + 4 <= len; c += 4) {
            int sp0 = __builtin_amdgcn_readlane(s_l, c);
            int sp1 = __builtin_amdgcn_readlane(s_l, c + 1);
            int sp2 = __builtin_amdgcn_readlane(s_l, c + 2);
            int sp3 = __builtin_amdgcn_readlane(s_l, c + 3);
            unsigned short u0 = *((const unsigned short*)(hq + (size_t)sp0 * 128) + lane);
            unsigned short u1 = *((const unsigned short*)(hq + (size_t)sp1 * 128) + lane);
            unsigned short u2 = *((const unsigned short*)(hq + (size_t)sp2 * 128) + lane);
            unsigned short u3 = *((const unsigned short*)(hq + (size_t)sp3 * 128) + lane);
            float w0 = rl_f(w_l, c), w1 = rl_f(w_l, c + 1);
            float w2 = rl_f(w_l, c + 2), w3 = rl_f(w_l, c + 3);
            f32x2 p0 = __builtin_amdgcn_cvt_pk_f32_fp8((int)u0, false);
            f32x2 p1 = __builtin_amdgcn_cvt_pk_f32_fp8((int)u1, false);
            f32x2 p2 = __builtin_amdgcn_cvt_pk_f32_fp8((int)u2, false);
            f32x2 p3 = __builtin_amdgcn_cvt_pk_f32_fp8((int)u3, false);
            acc0 += w0 * p0.x; acc1 += w0 * p0.y;
            acc0 += w1 * p1.x; acc1 += w1 * p1.y;
            acc0 += w2 * p2.x; acc1 += w2 * p2.y;
            acc0 += w3 * p3.x; acc1 += w3 * p3.y;
        }
        for (; c < len; c++) {
            int sp0 = __builtin_amdgcn_readlane(s_l, c);
            float w0 = rl_f(w_l, c);
            unsigned short u0 = *((const unsigned short*)(hq + (size_t)sp0 * 128) + lane);
            f32x2 p0 = __builtin_amdgcn_cvt_pk_f32_fp8((int)u0, false);
            acc0 += w0 * p0.x; acc1 += w0 * p0.y;
        }
    }
    float v0 = acc0 + bias[lane * 2];
    float v1 = acc1 + bias[lane * 2 + 1];
    v0 = v0 > 0.f ? v0 : (__expf(v0) - 1.f);
    v1 = v1 > 0.f ? v1 : (__expf(v1) - 1.f);
    float2 pv = {v0, v1};
    *(float2*)&out[(size_t)n * 128 + lane * 2] = pv;
}

// ---------------- mean pool + final GEMV (fused via done-counter) -------------
__global__ __launch_bounds__(256) void pool_final_kernel(const float* __restrict__ o2,
                                                         float* __restrict__ pool,
                                                         int* __restrict__ done,
                                                         const float* __restrict__ Wout,
                                                         const float* __restrict__ bout,
                                                         float* __restrict__ out,
                                                         int N, int nblocks, float invN) {
    __shared__ float4 sred[256];
    int f4 = threadIdx.x & 31;
    int r = blockIdx.x * 256 + (threadIdx.x >> 5);
    float4 acc = {0.f, 0.f, 0.f, 0.f};
    for (int i = 0; i < 32; i++, r += 8) {
        if (r < N) {
            float4 v = *(const float4*)&o2[(size_t)r * 128 + f4 * 4];
            acc.x += v.x; acc.y += v.y; acc.z += v.z; acc.w += v.w;
        }
    }
    sred[threadIdx.x] = acc;
    __syncthreads();
    if (threadIdx.x < 32) {
        float4 t = sred[threadIdx.x];
#pragma unroll
        for (int k = 1; k < 8; k++) {
            float4 u = sred[threadIdx.x + 32 * k];
            t.x += u.x; t.y += u.y; t.z += u.z; t.w += u.w;
        }
        atomicAdd(&pool[f4 * 4 + 0], t.x);
        atomicAdd(&pool[f4 * 4 + 1], t.y);
        atomicAdd(&pool[f4 * 4 + 2], t.z);
        atomicAdd(&pool[f4 * 4 + 3], t.w);
    }
    __threadfence();
    __shared__ int isLast;
    if (threadIdx.x == 0) isLast = (atomicAdd(done, 1) == nblocks - 1);
    __syncthreads();
    if (isLast) {
        __shared__ float spool[128];
        if (threadIdx.x < 128) spool[threadIdx.x] = atomicAdd(&pool[threadIdx.x], 0.f);
        __syncthreads();
        int o = threadIdx.x;
        float a = 0.f;
        for (int k = 0; k < 128; k++) a += spool[k] * Wout[k * 256 + o];
        out[o] = a * invN + bout[o];
    }
}

// ---------------- launch ------------------------------------------------------
extern "C" void kernel_launch(void* const* d_in, const int* in_sizes, int n_in,
                              void* d_out, int out_size, void* d_ws, size_t ws_size,
                              hipStream_t stream) {
    const float* x      = (const float*)d_in[0];
    const int*   ei     = (const int*)d_in[1];
    const float* W_emb  = (const float*)d_in[2];
    const float* b_emb  = (const float*)d_in[3];
    const float* W1     = (const float*)d_in[4];
    const float* a1_src = (const float*)d_in[5];
    const float* a1_dst = (const float*)d_in[6];
    const float* b1     = (const float*)d_in[7];
    const float* W2     = (const float*)d_in[8];
    const float* a2_src = (const float*)d_in[9];
    const float* a2_dst = (const float*)d_in[10];
    const float* b2     = (const float*)d_in[11];
    const float* W_out  = (const float*)d_in[12];
    const float* b_out  = (const float*)d_in[13];
    float* out = (float*)d_out;

    const int N = in_sizes[0] / 64;   // 25000
    const int E = in_sizes[1] / 2;    // 400000
    const int Etot = E + N;
    const int nb = (N + 255) / 256;

    char* ws = (char*)d_ws;
    size_t off = 0;
    auto alloc = [&](size_t bytes) -> void* {
        void* p = ws + off;
        off = (off + bytes + 255) & ~(size_t)255;
        return p;
    };
    typedef unsigned short u16;
    u16* xb    = (u16*)alloc((size_t)N * 64 * 2);
    u16* WeT   = (u16*)alloc((size_t)128 * 64 * 2);
    u16* W1T   = (u16*)alloc((size_t)512 * 128 * 2);
    u16* W2T   = (u16*)alloc((size_t)128 * 512 * 2);
    unsigned char* h1q = (unsigned char*)alloc((size_t)N * 512);   // fp8
    u16* o1b   = (u16*)alloc((size_t)N * 512 * 2);
    unsigned char* h2q = (unsigned char*)alloc((size_t)N * 128);   // fp8
    float* o2  = (float*)alloc((size_t)N * 128 * 4);
    float* as1 = (float*)alloc((size_t)N * 4 * 4);
    float* ad1 = (float*)alloc((size_t)N * 4 * 4);
    float* as2 = (float*)alloc((size_t)N * 4);
    float* ad2 = (float*)alloc((size_t)N * 4);
    float* pool = (float*)alloc(128 * 4);
    int* done   = (int*)alloc(256);
    int* rowptr = (int*)alloc((size_t)(N + 1) * 4);
    int* deg    = (int*)alloc((size_t)N * 4);
    int* cursor = (int*)alloc((size_t)N * 4);
    int* bsum   = (int*)alloc(128 * 4);
    int* boff   = (int*)alloc(128 * 4);
    int* esrc   = (int*)alloc((size_t)Etot * 4);

    // zero scratch + CSR build
    zero_kernel<<<(2 * N + 129 + 255) / 256, 256, 0, stream>>>(deg, cursor, pool, done, N);
    int blocksE = (Etot + 255) / 256;
    deg_count_kernel<<<blocksE, 256, 0, stream>>>(ei, E, N, deg);
    scan_pass1<<<nb, 256, 0, stream>>>(deg, rowptr, bsum, N);
    scan_pass2<<<1, 128, 0, stream>>>(bsum, boff, rowptr, nb, N);
    scan_pass3<<<nb, 256, 0, stream>>>(rowptr, boff, N);
    scatter_kernel<<<blocksE, 256, 0, stream>>>(ei, E, N, rowptr, cursor, esrc);

    // bf16 conversions + weight transposes
    int Nx = N * 64;
    int prep_elems = Nx + 64 * 128 + 128 * 512 + 512 * 128;
    prep_kernel<<<(prep_elems + 255) / 256, 256, 0, stream>>>(x, W_emb, W1, W2, xb, WeT, W1T, W2T, Nx);

    int mtiles = (N + 127) / 128;
    // fused: h1pre = relu(x@We+be)@W1  [N,512] fp8 + alpha1 (f32-exact)
    gemm12_fused<<<dim3(4, mtiles), 256, 0, stream>>>(xb, WeT, b_emb, W1T, h1q,
                                                      a1_src, a1_dst, as1, ad1, N);

    // layer-1 aggregation (logits on the fly, fp8 gather)
    gat_agg_l1<<<(N + 3) / 4, 256, 0, stream>>>((const unsigned*)h1q, (const float4*)as1,
                                                (const float4*)ad1, rowptr, esrc, b1, o1b, N);

    // h2pre = o1 @ W2  [N,128] fp8 + fused alpha2
    gemm_mfma_nt<0, 1, 1, 1><<<dim3(1, mtiles), 256, 0, stream>>>(
        o1b, W2T, nullptr, h2q, a2_src, a2_dst, as2, ad2, N, 128, 512);

    // layer-2 aggregation
    gat_agg_l2<<<(N + 3) / 4, 256, 0, stream>>>(h2q, as2, ad2, rowptr, esrc, b2, o2, N);

    // mean pool + final GEMV
    int npb = (N + 255) / 256;
    pool_final_kernel<<<npb, 256, 0, stream>>>(o2, pool, done, W_out, b_out, out,
                                               N, npb, 1.f / (float)N);
}